// Round 5
// baseline (976.367 us; speedup 1.0000x reference)
//
#include <hip/hip_runtime.h>
#include <hip/hip_bf16.h>
#include <cstdint>

#define NN 40000
#define NE 100000
#define NEP 100096          // NE padded to multiple of 64 (and of 32*8 waves)
#define NB 1024

typedef _Float16 halfT;
typedef _Float16 half8 __attribute__((ext_vector_type(8)));
typedef float f32x4 __attribute__((ext_vector_type(4)));

static __device__ __forceinline__ float sigf(float x){ return 1.f/(1.f + expf(-x)); }

// ---------------- node embed: h = relu(x @ lin0_W^T + b) ----------------
__global__ __launch_bounds__(256) void k_lin0(const float* __restrict__ x,
    const float* __restrict__ W, const float* __restrict__ b, float* __restrict__ h){
    int gid = blockIdx.x * 256 + threadIdx.x;           // NN*32 threads
    int i = gid >> 5, c = gid & 31;
    const float* xr = x + (size_t)i * 30;
    const float* wr = W + (size_t)c * 30;
    float s = b[c];
    #pragma unroll
    for (int f = 0; f < 30; f++) s += xr[f] * wr[f];
    h[gid] = fmaxf(s, 0.f);
}

// ---------------- edge MLP layer 1: ehh = relu(edge_attr @ W1^T + b1) fp16, zero-pad rows
__global__ __launch_bounds__(256) void k_edge_mlp(const float* __restrict__ ea,
    const float* __restrict__ W1, const float* __restrict__ b1, halfT* __restrict__ eh){
    int gid = blockIdx.x * 256 + threadIdx.x;           // NEP*128 threads
    int e = gid >> 7, hh = gid & 127;
    if (e >= NE){ eh[gid] = (halfT)0.f; return; }
    const float* xr = ea + (size_t)e * 11;
    const float* wr = W1 + (size_t)hh * 11;
    float s = b1[hh];
    #pragma unroll
    for (int f = 0; f < 11; f++) s += xr[f] * wr[f];
    eh[gid] = (halfT)fmaxf(s, 0.f);
}

// ---------------- B-matrix prep: Bp[p][k] = W2[j(p)][k] fp16, p = o*32+c, j = c*32+o
__global__ __launch_bounds__(256) void k_prepB(const float* __restrict__ W2, halfT* __restrict__ Bp){
    int gid = blockIdx.x * 256 + threadIdx.x;           // 1024*128 threads
    int p = gid >> 7, k = gid & 127;
    int j = ((p & 31) << 5) | (p >> 5);
    Bp[gid] = (halfT)W2[(size_t)j * 128 + k];
}
// p-ordered bias: bias_p[p] = b2[j(p)]
__global__ __launch_bounds__(256) void k_prepBias(const float* __restrict__ b2, float* __restrict__ bias_p){
    int p = blockIdx.x * 256 + threadIdx.x;             // 1024 threads
    bias_p[p] = b2[((p & 31) << 5) | (p >> 5)];
}

// ---------------- degree & graph counts ----------------
__global__ __launch_bounds__(256) void k_deg(const int* __restrict__ dst, float* __restrict__ deg, int E){
    int e = blockIdx.x * 256 + threadIdx.x;
    if (e < E) atomicAdd(&deg[dst[e]], 1.f);
}
__global__ __launch_bounds__(256) void k_counts(const int* __restrict__ batch, int* __restrict__ counts, int N){
    int i = blockIdx.x * 256 + threadIdx.x;
    if (i < N) atomicAdd(&counts[batch[i]], 1);
}
__global__ __launch_bounds__(1024) void k_scan(const int* __restrict__ counts, int* __restrict__ starts){
    __shared__ int s[1024];
    int t = threadIdx.x;
    s[t] = counts[t];
    __syncthreads();
    for (int off = 1; off < 1024; off <<= 1){
        int v = (t >= off) ? s[t - off] : 0;
        __syncthreads();
        s[t] += v;
        __syncthreads();
    }
    starts[t] = s[t] - counts[t];
    if (t == 1023) starts[1024] = s[1023];
}

// ---------------- fused NNConv message pass, v2: barrier-free, LDS-free ----------------
// One wave owns 32 edges (two 16-edge MFMA B-fragments, resident).
// Swapped operands: D = Bp(16 p-rows) x eh(16 edges)^T per mfma, so D col = edge,
// D row = p-row. p = o*32 + c (o-major) => contraction over c is 4 in-lane FMAs
// (+ bias via p-ordered float4) and a 2-step shfl_xor(16/32) reduce over q=l>>4.
// Layouts (round-3/4 verified): A row=l&15, k=(l>>4)*8+i; B col=l&15; D col=l&15, row=(l>>4)*4+r.
__global__ __launch_bounds__(256) void k_msg2(const halfT* __restrict__ ehh,
    const halfT* __restrict__ Bp, const float* __restrict__ bias_p,
    const float* __restrict__ h, const int* __restrict__ src, const int* __restrict__ dst,
    float* __restrict__ aggr){
    int wid = (blockIdx.x * 256 + threadIdx.x) >> 6;
    int l = threadIdx.x & 63;
    int ebase = wid * 32;
    int m = l & 15, q = l >> 4;
    int e0 = ebase + m, e1 = ebase + 16 + m;
    int s0i = (e0 < NE) ? src[e0] : 0;
    int s1i = (e1 < NE) ? src[e1] : 0;
    // resident B-fragments: this wave's 32 edges
    half8 b0[4], b1[4];
    const halfT* B0 = ehh + (size_t)e0 * 128 + q * 8;
    const halfT* B1 = ehh + (size_t)e1 * 128 + q * 8;
    #pragma unroll
    for (int ks = 0; ks < 4; ks++){
        b0[ks] = *(const half8*)(B0 + ks * 32);
        b1[ks] = *(const half8*)(B1 + ks * 32);
    }
    // u = h[src[e]] slices this lane needs: c = wn*16 + q*4 + r
    float4 u0a = *(const float4*)(h + (size_t)s0i * 32 + q * 4);
    float4 u0b = *(const float4*)(h + (size_t)s0i * 32 + 16 + q * 4);
    float4 u1a = *(const float4*)(h + (size_t)s1i * 32 + q * 4);
    float4 u1b = *(const float4*)(h + (size_t)s1i * 32 + 16 + q * 4);
    int da = 0; bool aok = false;
    if (l < 32 && (ebase + l) < NE){ da = dst[ebase + l]; aok = true; }
    const halfT* A0 = Bp + (size_t)m * 128 + q * 8;
    #pragma unroll 1
    for (int o = 0; o < 32; o++){
        // load both 16-row p-windows of this o up front (latency overlap)
        const halfT* ApA = A0 + (size_t)(o * 32) * 128;
        const halfT* ApB = ApA + (size_t)16 * 128;
        half8 aA[4], aB[4];
        #pragma unroll
        for (int ks = 0; ks < 4; ks++){
            aA[ks] = *(const half8*)(ApA + ks * 32);
            aB[ks] = *(const half8*)(ApB + ks * 32);
        }
        float4 bvA = *(const float4*)(bias_p + o * 32 + q * 4);
        float4 bvB = *(const float4*)(bias_p + o * 32 + 16 + q * 4);
        f32x4 accA0 = {0,0,0,0}, accA1 = {0,0,0,0};
        f32x4 accB0 = {0,0,0,0}, accB1 = {0,0,0,0};
        #pragma unroll
        for (int ks = 0; ks < 4; ks++){
            accA0 = __builtin_amdgcn_mfma_f32_16x16x32_f16(aA[ks], b0[ks], accA0, 0, 0, 0);
            accA1 = __builtin_amdgcn_mfma_f32_16x16x32_f16(aA[ks], b1[ks], accA1, 0, 0, 0);
            accB0 = __builtin_amdgcn_mfma_f32_16x16x32_f16(aB[ks], b0[ks], accB0, 0, 0, 0);
            accB1 = __builtin_amdgcn_mfma_f32_16x16x32_f16(aB[ks], b1[ks], accB1, 0, 0, 0);
        }
        float s0 = (accA0[0] + bvA.x) * u0a.x + (accA0[1] + bvA.y) * u0a.y
                 + (accA0[2] + bvA.z) * u0a.z + (accA0[3] + bvA.w) * u0a.w
                 + (accB0[0] + bvB.x) * u0b.x + (accB0[1] + bvB.y) * u0b.y
                 + (accB0[2] + bvB.z) * u0b.z + (accB0[3] + bvB.w) * u0b.w;
        float s1 = (accA1[0] + bvA.x) * u1a.x + (accA1[1] + bvA.y) * u1a.y
                 + (accA1[2] + bvA.z) * u1a.z + (accA1[3] + bvA.w) * u1a.w
                 + (accB1[0] + bvB.x) * u1b.x + (accB1[1] + bvB.y) * u1b.y
                 + (accB1[2] + bvB.z) * u1b.z + (accB1[3] + bvB.w) * u1b.w;
        s0 += __shfl_xor(s0, 16); s0 += __shfl_xor(s0, 32);
        s1 += __shfl_xor(s1, 16); s1 += __shfl_xor(s1, 32);
        if (aok){
            float sv = (l < 16) ? s0 : s1;
            atomicAdd(&aggr[(size_t)da * 32 + o], sv);
        }
    }
}

// ---------------- fused NNConv-epilogue + GRU: h = GRU(m, h) ----------------
__global__ __launch_bounds__(256) void k_gru(const float* __restrict__ aggr,
    const float* __restrict__ deg, float* __restrict__ h,
    const float* __restrict__ rootW, const float* __restrict__ cb,
    const float* __restrict__ Wih, const float* __restrict__ Whh,
    const float* __restrict__ bih, const float* __restrict__ bhh){
    __shared__ float s_root[1024];
    __shared__ float s_wih[3072];
    __shared__ float s_whh[3072];
    __shared__ float s_bih[96], s_bhh[96], s_cb[32];
    int tid = threadIdx.x;
    for (int idx = tid; idx < 1024; idx += 256) s_root[idx] = rootW[idx];
    for (int idx = tid; idx < 3072; idx += 256){ s_wih[idx] = Wih[idx]; s_whh[idx] = Whh[idx]; }
    if (tid < 96){ s_bih[tid] = bih[tid]; s_bhh[tid] = bhh[tid]; }
    if (tid < 32) s_cb[tid] = cb[tid];
    __syncthreads();
    int i = blockIdx.x * 256 + tid;
    if (i >= NN) return;
    float hq[32], mv[32], hn[32];
    const float* hr = h + (size_t)i * 32;
    #pragma unroll
    for (int k = 0; k < 8; k++) *(float4*)&hq[k * 4] = *(const float4*)(hr + k * 4);
    float invd = 1.f / fmaxf(deg[i], 1.f);
    const float* ar = aggr + (size_t)i * 32;
    #pragma unroll
    for (int c = 0; c < 32; c++){
        float s = ar[c] * invd + s_cb[c];
        #pragma unroll
        for (int k = 0; k < 32; k++) s += hq[k] * s_root[k * 32 + c];
        mv[c] = fmaxf(s, 0.f);
    }
    for (int j = 0; j < 32; j++){
        float gxr = s_bih[j], ghr = s_bhh[j];
        float gxz = s_bih[32 + j], ghz = s_bhh[32 + j];
        float gxn = s_bih[64 + j], ghn = s_bhh[64 + j];
        const float* wr0 = &s_wih[j * 32];
        const float* wr1 = &s_wih[(32 + j) * 32];
        const float* wr2 = &s_wih[(64 + j) * 32];
        const float* wh0 = &s_whh[j * 32];
        const float* wh1 = &s_whh[(32 + j) * 32];
        const float* wh2 = &s_whh[(64 + j) * 32];
        #pragma unroll
        for (int k = 0; k < 32; k++){
            float mm = mv[k], hh = hq[k];
            gxr += mm * wr0[k]; ghr += hh * wh0[k];
            gxz += mm * wr1[k]; ghz += hh * wh1[k];
            gxn += mm * wr2[k]; ghn += hh * wh2[k];
        }
        float r = sigf(gxr + ghr);
        float z = sigf(gxz + ghz);
        float n = tanhf(gxn + r * ghn);
        hn[j] = (1.f - z) * n + z * hq[j];
    }
    float* hw = h + (size_t)i * 32;
    #pragma unroll
    for (int k = 0; k < 8; k++) *(float4*)(hw + k * 4) = *(const float4*)&hn[k * 4];
}

// ---------------- Set2Set LSTM step (block per graph) ----------------
__global__ __launch_bounds__(128) void k_lstm(const float* __restrict__ q_star,
    float* __restrict__ hs, float* __restrict__ cs,
    const float* __restrict__ Wih, const float* __restrict__ Whh,
    const float* __restrict__ bih, const float* __restrict__ bhh){
    __shared__ float gbuf[128];
    int g = blockIdx.x, j = threadIdx.x;
    const float* q = q_star + (size_t)g * 64;
    const float* wr = Wih + (size_t)j * 64;
    float acc = bih[j] + bhh[j];
    #pragma unroll 8
    for (int k = 0; k < 64; k++) acc += q[k] * wr[k];
    const float* hr = hs + (size_t)g * 32;
    const float* wh = Whh + (size_t)j * 32;
    #pragma unroll 8
    for (int k = 0; k < 32; k++) acc += hr[k] * wh[k];
    gbuf[j] = acc;
    __syncthreads();
    if (j < 32){
        float iv = sigf(gbuf[j]);
        float fv = sigf(gbuf[32 + j]);
        float gv = tanhf(gbuf[64 + j]);
        float ov = sigf(gbuf[96 + j]);
        float cn = fv * cs[(size_t)g * 32 + j] + iv * gv;
        cs[(size_t)g * 32 + j] = cn;
        hs[(size_t)g * 32 + j] = ov * tanhf(cn);
    }
}

// ---------------- attention pooling (block=64 per graph) ----------------
__global__ __launch_bounds__(64) void k_attn(const float* __restrict__ h, const float* __restrict__ hs,
    const int* __restrict__ starts, float* __restrict__ e_buf, float* __restrict__ q_star){
    int g = blockIdx.x, l = threadIdx.x;
    int s0 = starts[g], s1 = starts[g + 1];
    int c = l & 31, grp = l >> 5;
    float hsv = hs[(size_t)g * 32 + c];
    float mx = -3.4e38f;
    for (int i = s0 + grp; i < s1; i += 2){
        float p = h[(size_t)i * 32 + c] * hsv;
        #pragma unroll
        for (int off = 1; off < 32; off <<= 1) p += __shfl_xor(p, off);
        if (c == 0) e_buf[i] = p;
        mx = fmaxf(mx, p);
    }
    mx = fmaxf(mx, __shfl_xor(mx, 32));
    float ssum = 0.f;
    for (int i = s0 + grp; i < s1; i += 2){
        if (c == 0) ssum += expf(e_buf[i] - mx);
    }
    #pragma unroll
    for (int off = 1; off < 64; off <<= 1) ssum += __shfl_xor(ssum, off);
    float inv = (ssum > 0.f) ? 1.f / ssum : 0.f;
    float acc = 0.f;
    for (int i = s0 + grp; i < s1; i += 2){
        float a = expf(e_buf[i] - mx) * inv;
        acc += a * h[(size_t)i * 32 + c];
    }
    acc += __shfl_xor(acc, 32);
    if (l < 32){
        q_star[(size_t)g * 64 + 32 + c] = acc;
        q_star[(size_t)g * 64 + c] = hsv;
    }
}

// ---------------- final: out = relu(q_star@lin1^T+b1) @ lin2^T + b2 ----------------
__global__ __launch_bounds__(64) void k_final(const float* __restrict__ q_star,
    const float* __restrict__ W1, const float* __restrict__ b1,
    const float* __restrict__ W2, const float* __restrict__ b2, float* __restrict__ out){
    int g = blockIdx.x, l = threadIdx.x;
    float p = 0.f;
    if (l < 32){
        const float* q = q_star + (size_t)g * 64;
        const float* wr = W1 + (size_t)l * 64;
        float s = b1[l];
        #pragma unroll 8
        for (int k = 0; k < 64; k++) s += q[k] * wr[k];
        p = fmaxf(s, 0.f) * W2[l];
    }
    #pragma unroll
    for (int off = 1; off < 64; off <<= 1) p += __shfl_xor(p, off);
    if (l == 0) out[g] = p + b2[0];
}

extern "C" void kernel_launch(void* const* d_in, const int* in_sizes, int n_in,
                              void* d_out, int out_size, void* d_ws, size_t ws_size,
                              hipStream_t stream){
    (void)in_sizes; (void)n_in; (void)out_size;
    const float* x        = (const float*)d_in[0];
    const float* ea       = (const float*)d_in[1];
    const int*   ei       = (const int*)d_in[2];
    const int*   batch    = (const int*)d_in[3];
    const float* lin0_W   = (const float*)d_in[4];
    const float* lin0_b   = (const float*)d_in[5];
    const float* mlp_W1   = (const float*)d_in[6];
    const float* mlp_b1   = (const float*)d_in[7];
    const float* mlp_W2   = (const float*)d_in[8];
    const float* mlp_b2   = (const float*)d_in[9];
    const float* root_W   = (const float*)d_in[10];
    const float* conv_b   = (const float*)d_in[11];
    const float* gWih     = (const float*)d_in[12];
    const float* gWhh     = (const float*)d_in[13];
    const float* gbih     = (const float*)d_in[14];
    const float* gbhh     = (const float*)d_in[15];
    const float* lWih     = (const float*)d_in[16];
    const float* lWhh     = (const float*)d_in[17];
    const float* lbih     = (const float*)d_in[18];
    const float* lbhh     = (const float*)d_in[19];
    const float* lin1_W   = (const float*)d_in[20];
    const float* lin1_b   = (const float*)d_in[21];
    const float* lin2_W   = (const float*)d_in[22];
    const float* lin2_b   = (const float*)d_in[23];
    const int* src = ei;
    const int* dst = ei + NE;
    float* out = (float*)d_out;

    char* w = (char*)d_ws;
    size_t off = 0;
    auto alloc = [&](size_t bytes) -> void* {
        void* p = w + off;
        off = (off + bytes + 255) & ~(size_t)255;
        return p;
    };
    float* h      = (float*)alloc((size_t)NN * 32 * 4);
    float* aggr   = (float*)alloc((size_t)NN * 32 * 4);
    float* deg    = (float*)alloc((size_t)NN * 4);
    float* e_buf  = (float*)alloc((size_t)NN * 4);
    int*   counts = (int*)alloc((size_t)NB * 4);
    int*   starts = (int*)alloc((size_t)(NB + 1) * 4);
    float* q_star = (float*)alloc((size_t)NB * 64 * 4);
    float* hs     = (float*)alloc((size_t)NB * 32 * 4);
    float* cs     = (float*)alloc((size_t)NB * 32 * 4);
    halfT* ehh    = (halfT*)alloc((size_t)NEP * 128 * 2);
    halfT* Bp     = (halfT*)alloc((size_t)1024 * 128 * 2);
    float* bias_p = (float*)alloc((size_t)1024 * 4);
    if (ws_size < off) return;   // cannot run

    hipMemsetAsync(deg, 0, (size_t)NN * 4, stream);
    hipMemsetAsync(counts, 0, (size_t)NB * 4, stream);
    hipMemsetAsync(q_star, 0, (size_t)NB * 64 * 4, stream);
    hipMemsetAsync(hs, 0, (size_t)NB * 32 * 4, stream);
    hipMemsetAsync(cs, 0, (size_t)NB * 32 * 4, stream);

    k_lin0<<<(NN * 32) / 256, 256, 0, stream>>>(x, lin0_W, lin0_b, h);
    k_edge_mlp<<<(NEP * 128) / 256, 256, 0, stream>>>(ea, mlp_W1, mlp_b1, ehh);
    k_prepB<<<(1024 * 128) / 256, 256, 0, stream>>>(mlp_W2, Bp);
    k_prepBias<<<4, 256, 0, stream>>>(mlp_b2, bias_p);
    k_deg<<<(NE + 255) / 256, 256, 0, stream>>>(dst, deg, NE);
    k_counts<<<(NN + 255) / 256, 256, 0, stream>>>(batch, counts, NN);
    k_scan<<<1, 1024, 0, stream>>>(counts, starts);

    int nwaves = (NE + 31) / 32;                  // 3125
    int nblocks = (nwaves + 3) / 4;               // 4 waves per 256-thread block
    for (int t = 0; t < 3; t++){
        hipMemsetAsync(aggr, 0, (size_t)NN * 32 * 4, stream);
        k_msg2<<<nblocks, 256, 0, stream>>>(ehh, Bp, bias_p, h, src, dst, aggr);
        k_gru<<<(NN + 255) / 256, 256, 0, stream>>>(aggr, deg, h, root_W, conv_b,
                                                    gWih, gWhh, gbih, gbhh);
    }

    for (int t = 0; t < 3; t++){
        k_lstm<<<NB, 128, 0, stream>>>(q_star, hs, cs, lWih, lWhh, lbih, lbhh);
        k_attn<<<NB, 64, 0, stream>>>(h, hs, starts, e_buf, q_star);
    }
    k_final<<<NB, 64, 0, stream>>>(q_star, lin1_W, lin1_b, lin2_W, lin2_b, out);
}

// Round 6
// 452.537 us; speedup vs baseline: 2.1575x; 2.1575x over previous
//
#include <hip/hip_runtime.h>
#include <hip/hip_bf16.h>
#include <cstdint>

#define NN 40000
#define NE 100000
#define NEP 100096           // 32-aligned edge count
#define NB 1024

typedef _Float16 halfT;
typedef _Float16 half8 __attribute__((ext_vector_type(8)));
typedef float f32x4 __attribute__((ext_vector_type(4)));

static __device__ __forceinline__ float sigf(float x){ return 1.f/(1.f + expf(-x)); }

// =====================================================================
// k_setup: one kernel, 5 block-ranges
//  R0 [0,5000):       h = relu(x@lin0^T+b) -> h fp32 + hH fp16
//  R1 [5000,55048):   eh fp16 in MFMA-fragment order ehF
//  R2 [55048,55564):  BfF: W2 repacked into B-fragment stream (129 K-tiles, 2 n-tiles)
//  R3 [55564,55955):  deg atomics
//  R4 [55955,56035):  weight transposes for gru/s2s
// ehF layout:  ehF[(((g16*4+s)*64 + m*4+q))*8 + i] = eh[g16*16+m][32s+q*8+i]
// BfF layout:  BfF[(((ks*2+nt)*64 + m*4+q))*8 + i] =
//                ks<128 : W2[(ks>>2)*32 + nt*16+m][32*(ks&3)+q*8+i]
//                ks==128: b2[(q*8+i)*32 + nt*16+m]          (bias K-tile)
// =====================================================================
__global__ __launch_bounds__(256) void k_setup(
    const float* __restrict__ x, const float* __restrict__ lin0_W, const float* __restrict__ lin0_b,
    const float* __restrict__ ea, const float* __restrict__ W1, const float* __restrict__ b1,
    const float* __restrict__ W2, const float* __restrict__ b2,
    const int* __restrict__ dstA,
    const float* __restrict__ gWih, const float* __restrict__ gWhh,
    const float* __restrict__ lWih, const float* __restrict__ lWhh, const float* __restrict__ lin1_W,
    float* __restrict__ h, halfT* __restrict__ hH, halfT* __restrict__ ehF, halfT* __restrict__ BfF,
    float* __restrict__ deg, float* __restrict__ WgT, float* __restrict__ WhT,
    float* __restrict__ lWihT, float* __restrict__ lWhhT, float* __restrict__ lin1T)
{
    int b = blockIdx.x, tid = threadIdx.x;
    if (b < 5000){
        int gid = b * 256 + tid;            // NN*32
        int i = gid >> 5, c = gid & 31;
        const float* xr = x + (size_t)i * 30;
        const float* wr = lin0_W + (size_t)c * 30;
        float s = lin0_b[c];
        #pragma unroll
        for (int f = 0; f < 30; f++) s += xr[f] * wr[f];
        s = fmaxf(s, 0.f);
        h[gid] = s; hH[gid] = (halfT)s;
    } else if (b < 55048){
        int gid = (b - 5000) * 256 + tid;   // NEP*128
        int i8 = gid & 7;
        int ch = (gid >> 3) & 63;
        int s4 = (gid >> 9) & 3;
        int g16 = gid >> 11;
        int m = ch >> 2, q = ch & 3;
        int e = g16 * 16 + m;
        int k = 32 * s4 + q * 8 + i8;
        halfT v = (halfT)0.f;
        if (e < NE){
            const float* xr = ea + (size_t)e * 11;
            const float* wr = W1 + (size_t)k * 11;
            float s = b1[k];
            #pragma unroll
            for (int f = 0; f < 11; f++) s += xr[f] * wr[f];
            v = (halfT)fmaxf(s, 0.f);
        }
        ehF[gid] = v;
    } else if (b < 55564){
        int gid = (b - 55048) * 256 + tid;  // 129*2*64*8 = 132096
        int i8 = gid & 7;
        int ch = (gid >> 3) & 63;
        int nt = (gid >> 9) & 1;
        int ks = gid >> 10;
        int m = ch >> 2, q = ch & 3;
        int o = nt * 16 + m;
        float v;
        if (ks < 128){
            int c = ks >> 2;
            int k = 32 * (ks & 3) + q * 8 + i8;
            v = W2[(size_t)(c * 32 + o) * 128 + k];
        } else {
            int c = q * 8 + i8;
            v = b2[c * 32 + o];
        }
        BfF[gid] = (halfT)v;
    } else if (b < 55955){
        int e = (b - 55564) * 256 + tid;
        if (e < NE) atomicAdd(&deg[dstA[e]], 1.f);
    } else {
        int t = (b - 55955) * 256 + tid;    // 20480
        if (t < 3072){ int k = t / 96, j = t % 96; WgT[t] = gWih[(size_t)j * 32 + k]; }
        else if (t < 6144){ int t2 = t - 3072; int k = t2 / 96, j = t2 % 96; WhT[t2] = gWhh[(size_t)j * 32 + k]; }
        else if (t < 14336){ int t2 = t - 6144; int k = t2 >> 7, j = t2 & 127; lWihT[t2] = lWih[(size_t)j * 64 + k]; }
        else if (t < 18432){ int t2 = t - 14336; int k = t2 >> 7, j = t2 & 127; lWhhT[t2] = lWhh[(size_t)j * 32 + k]; }
        else { int t2 = t - 18432; int k = t2 >> 5, c = t2 & 31; lin1T[t2] = lin1_W[(size_t)c * 64 + k]; }
    }
}

// ---------------- starts[g] = lower_bound(batch, g), batch is sorted ----------------
__global__ __launch_bounds__(256) void k_starts(const int* __restrict__ batch, int* __restrict__ starts){
    int g = blockIdx.x * 256 + threadIdx.x;
    if (g > NB) return;
    int lo = 0, hi = NN;
    while (lo < hi){
        int mid = (lo + hi) >> 1;
        if (batch[mid] < g) lo = mid + 1; else hi = mid;
    }
    starts[g] = lo;
}

// =====================================================================
// k_msg3: NNConv message pass as a K=4096(+32 bias) GEMM with on-the-fly
// A = u[e][c]*eh[e][k]. One wave = 32 edges (two 16-edge A-rows), N=32 (2 tiles).
// No LDS, no barriers. MFMA conventions identical to round-3-verified kernel:
//   A-frag: row = l&15, k-slot = (l>>4)*8+i ; B-frag: col(o) = l&15, same k-slot;
//   D: row = (l>>4)*4+r (A-row), col = l&15 (B-col).
// K decomposition: ck = ks*32 + q*8 + i  ->  c = ks>>2 (lane-uniform),
//                  k = 32*(ks&3) + q*8 + i.
// =====================================================================
__global__ __launch_bounds__(256) void k_msg3(
    const halfT* __restrict__ ehF, const halfT* __restrict__ BfF,
    const halfT* __restrict__ hH,
    const int* __restrict__ src, const int* __restrict__ dst,
    float* __restrict__ aggr)
{
    int wid = (blockIdx.x * 256 + threadIdx.x) >> 6;
    int l = threadIdx.x & 63;
    int m = l & 15, q = l >> 4;
    int eb = wid * 32;
    // u gather (fp16 h rows of the wave's 32 src nodes)
    half8 u0[4], u1[4], ub0, ub1;
    {
        int e0 = eb + m;      int se0 = (e0 < NE) ? src[e0] : 0;
        int e1 = eb + 16 + m; int se1 = (e1 < NE) ? src[e1] : 0;
        const halfT* p0 = hH + (size_t)se0 * 32;
        const halfT* p1 = hH + (size_t)se1 * 32;
        #pragma unroll
        for (int j = 0; j < 4; j++){
            u0[j] = *(const half8*)(p0 + j * 8);
            u1[j] = *(const half8*)(p1 + j * 8);
        }
        ub0 = *(const half8*)(p0 + q * 8);      // bias-tile A-frag: u[e][q*8+i]
        ub1 = *(const half8*)(p1 + q * 8);
    }
    // eh fragments (register-resident: lane only ever needs k in {32s+q*8..+7})
    half8 eh0[4], eh1[4];
    {
        int g0 = eb >> 4;
        #pragma unroll
        for (int s = 0; s < 4; s++){
            eh0[s] = *(const half8*)(ehF + ((size_t)(g0 * 4 + s) * 64 + (m * 4 + q)) * 8);
            eh1[s] = *(const half8*)(ehF + ((size_t)((g0 + 1) * 4 + s) * 64 + (m * 4 + q)) * 8);
        }
    }
    f32x4 acc00 = {0,0,0,0}, acc01 = {0,0,0,0}, acc10 = {0,0,0,0}, acc11 = {0,0,0,0};
    const halfT* bbase = BfF + (size_t)(m * 4 + q) * 8;
    #pragma unroll
    for (int ks = 0; ks < 128; ks++){
        half8 b0 = *(const half8*)(bbase + (size_t)(ks * 2 + 0) * 512);
        half8 b1 = *(const half8*)(bbase + (size_t)(ks * 2 + 1) * 512);
        const int c = ks >> 2, s = ks & 3;
        halfT uc0 = u0[c >> 3][c & 7];
        halfT uc1 = u1[c >> 3][c & 7];
        half8 a0 = eh0[s] * uc0;
        half8 a1 = eh1[s] * uc1;
        acc00 = __builtin_amdgcn_mfma_f32_16x16x32_f16(a0, b0, acc00, 0, 0, 0);
        acc01 = __builtin_amdgcn_mfma_f32_16x16x32_f16(a0, b1, acc01, 0, 0, 0);
        acc10 = __builtin_amdgcn_mfma_f32_16x16x32_f16(a1, b0, acc10, 0, 0, 0);
        acc11 = __builtin_amdgcn_mfma_f32_16x16x32_f16(a1, b1, acc11, 0, 0, 0);
    }
    {   // bias K-tile (ks = 128): msg += u[e][c]*b2[c*32+o]
        half8 b0 = *(const half8*)(bbase + (size_t)256 * 512);
        half8 b1 = *(const half8*)(bbase + (size_t)257 * 512);
        acc00 = __builtin_amdgcn_mfma_f32_16x16x32_f16(ub0, b0, acc00, 0, 0, 0);
        acc01 = __builtin_amdgcn_mfma_f32_16x16x32_f16(ub0, b1, acc01, 0, 0, 0);
        acc10 = __builtin_amdgcn_mfma_f32_16x16x32_f16(ub1, b0, acc10, 0, 0, 0);
        acc11 = __builtin_amdgcn_mfma_f32_16x16x32_f16(ub1, b1, acc11, 0, 0, 0);
    }
    // scatter: lane holds msg[e = eb+G*16+q*4+r][o = nt*16+m]
    #pragma unroll
    for (int r = 0; r < 4; r++){
        int ea0 = eb + q * 4 + r;
        if (ea0 < NE){
            int d = dst[ea0];
            atomicAdd(&aggr[(size_t)d * 32 + m],      acc00[r]);
            atomicAdd(&aggr[(size_t)d * 32 + 16 + m], acc01[r]);
        }
        int ea1 = eb + 16 + q * 4 + r;
        if (ea1 < NE){
            int d = dst[ea1];
            atomicAdd(&aggr[(size_t)d * 32 + m],      acc10[r]);
            atomicAdd(&aggr[(size_t)d * 32 + 16 + m], acc11[r]);
        }
    }
}

// =====================================================================
// k_gru: wave-parallel (lane = output channel, 32 lanes per node).
// Consumes aggr and re-zeroes it for the next iteration. Writes h + hH.
// =====================================================================
__global__ __launch_bounds__(256) void k_gru(
    float* __restrict__ aggr, const float* __restrict__ deg, float* __restrict__ h,
    halfT* __restrict__ hH,
    const float* __restrict__ rootW, const float* __restrict__ cb,
    const float* __restrict__ WgT, const float* __restrict__ WhT,
    const float* __restrict__ gbih, const float* __restrict__ gbhh)
{
    int tid = threadIdx.x;
    int i = blockIdx.x * 8 + (tid >> 5);
    int c = tid & 31;
    size_t base = (size_t)i * 32 + c;
    float hq = h[base];
    float av = aggr[base];
    aggr[base] = 0.f;                       // zero for next msg pass
    float invd = 1.f / fmaxf(deg[i], 1.f);
    float mv = av * invd + cb[c];
    #pragma unroll 8
    for (int k = 0; k < 32; k++)
        mv += __shfl(hq, k, 32) * rootW[k * 32 + c];
    mv = fmaxf(mv, 0.f);
    float gr = gbih[c],      hr = gbhh[c];
    float gz = gbih[32 + c], hz = gbhh[32 + c];
    float gn = gbih[64 + c], hn = gbhh[64 + c];
    #pragma unroll 4
    for (int k = 0; k < 32; k++){
        float mk = __shfl(mv, k, 32);
        float hk = __shfl(hq, k, 32);
        const float* wg = WgT + k * 96;
        const float* wh = WhT + k * 96;
        gr += mk * wg[c];      hr += hk * wh[c];
        gz += mk * wg[32 + c]; hz += hk * wh[32 + c];
        gn += mk * wg[64 + c]; hn += hk * wh[64 + c];
    }
    float r = sigf(gr + hr);
    float z = sigf(gz + hz);
    float n = tanhf(gn + r * hn);
    float hnew = (1.f - z) * n + z * hq;
    h[base] = hnew;
    hH[base] = (halfT)hnew;
}

// =====================================================================
// k_s2s: entire Set2Set (3x LSTM + attention) + final MLP. One wave per graph.
// State in registers: qs = q_star[l]; hs/cs live in lanes 0..31.
// =====================================================================
__global__ __launch_bounds__(64) void k_s2s(
    const float* __restrict__ h, const int* __restrict__ starts,
    const float* __restrict__ lWihT, const float* __restrict__ lWhhT,
    const float* __restrict__ lbih, const float* __restrict__ lbhh,
    const float* __restrict__ lin1T, const float* __restrict__ lin1_b,
    const float* __restrict__ lin2W, const float* __restrict__ lin2b,
    float* __restrict__ out)
{
    __shared__ float ebuf[256];
    int g = blockIdx.x, l = threadIdx.x;
    int s0 = starts[g], s1 = starts[g + 1];
    int c = l & 31, grp = l >> 5;
    float qs = 0.f, hsv = 0.f, csv = 0.f;
    for (int t = 0; t < 3; t++){
        // LSTM gates: lane computes j1=l, j2=l+64 (torch order i,f,g,o)
        float a1 = lbih[l] + lbhh[l];
        float a2 = lbih[l + 64] + lbhh[l + 64];
        #pragma unroll 8
        for (int k = 0; k < 64; k++){
            float qk = __shfl(qs, k);
            a1 += qk * lWihT[k * 128 + l];
            a2 += qk * lWihT[k * 128 + 64 + l];
        }
        #pragma unroll 8
        for (int k = 0; k < 32; k++){
            float hk = __shfl(qs, k);           // hs == q_star[:32]
            a1 += hk * lWhhT[k * 128 + l];
            a2 += hk * lWhhT[k * 128 + 64 + l];
        }
        float gate1 = sigf(a1);                          // i (l<32) / f (l>=32)
        float gate2 = (l < 32) ? tanhf(a2) : sigf(a2);   // g (l<32) / o (l>=32)
        float fv = __shfl(gate1, c + 32);
        float ov = __shfl(gate2, c + 32);
        if (l < 32){
            csv = fv * csv + gate1 * gate2;
            hsv = ov * tanhf(csv);
        }
        float hq = __shfl(hsv, c);              // broadcast hs[c] to both halves
        // attention: pass 1 (dots + max, cache dots in LDS)
        float mx = -3.4e38f;
        for (int idx = s0 + grp; idx < s1; idx += 2){
            float p = h[(size_t)idx * 32 + c] * hq;
            p += __shfl_xor(p, 1);  p += __shfl_xor(p, 2);
            p += __shfl_xor(p, 4);  p += __shfl_xor(p, 8);
            p += __shfl_xor(p, 16);
            int ii = idx - s0;
            if (c == 0 && ii < 256) ebuf[ii] = p;
            mx = fmaxf(mx, p);
        }
        mx = fmaxf(mx, __shfl_xor(mx, 32));
        __syncthreads();
        // pass 2: denom
        int n = s1 - s0;
        int nc = n < 256 ? n : 256;
        float ss = 0.f;
        for (int ii = l; ii < nc; ii += 64) ss += expf(ebuf[ii] - mx);
        for (int idx = s0 + 256 + grp; idx < s1; idx += 2){   // overflow (rare)
            float p = h[(size_t)idx * 32 + c] * hq;
            p += __shfl_xor(p, 1);  p += __shfl_xor(p, 2);
            p += __shfl_xor(p, 4);  p += __shfl_xor(p, 8);
            p += __shfl_xor(p, 16);
            if (c == 0) ss += expf(p - mx);
        }
        ss += __shfl_xor(ss, 1);  ss += __shfl_xor(ss, 2);
        ss += __shfl_xor(ss, 4);  ss += __shfl_xor(ss, 8);
        ss += __shfl_xor(ss, 16); ss += __shfl_xor(ss, 32);
        float inv = (ss > 0.f) ? 1.f / ss : 0.f;
        // pass 3: weighted sum
        float acc = 0.f;
        for (int idx = s0 + grp; idx < s1; idx += 2){
            int ii = idx - s0;
            float p;
            if (ii < 256) p = ebuf[ii];
            else {
                p = h[(size_t)idx * 32 + c] * hq;
                p += __shfl_xor(p, 1);  p += __shfl_xor(p, 2);
                p += __shfl_xor(p, 4);  p += __shfl_xor(p, 8);
                p += __shfl_xor(p, 16);
            }
            float a = expf(p - mx) * inv;
            acc += a * h[(size_t)idx * 32 + c];
        }
        acc += __shfl_xor(acc, 32);
        qs = (l < 32) ? hsv : acc;
        __syncthreads();
    }
    // final: out = relu(q_star@lin1^T+b1) @ lin2^T + b2
    float s = lin1_b[c];
    #pragma unroll 8
    for (int k = 0; k < 64; k++){
        float qk = __shfl(qs, k);
        s += qk * lin1T[k * 32 + c];
    }
    float pp = (l < 32) ? fmaxf(s, 0.f) * lin2W[c] : 0.f;
    pp += __shfl_xor(pp, 1);  pp += __shfl_xor(pp, 2);
    pp += __shfl_xor(pp, 4);  pp += __shfl_xor(pp, 8);
    pp += __shfl_xor(pp, 16); pp += __shfl_xor(pp, 32);
    if (l == 0) out[g] = pp + lin2b[0];
}

extern "C" void kernel_launch(void* const* d_in, const int* in_sizes, int n_in,
                              void* d_out, int out_size, void* d_ws, size_t ws_size,
                              hipStream_t stream){
    (void)in_sizes; (void)n_in; (void)out_size;
    const float* x        = (const float*)d_in[0];
    const float* ea       = (const float*)d_in[1];
    const int*   ei       = (const int*)d_in[2];
    const int*   batch    = (const int*)d_in[3];
    const float* lin0_W   = (const float*)d_in[4];
    const float* lin0_b   = (const float*)d_in[5];
    const float* mlp_W1   = (const float*)d_in[6];
    const float* mlp_b1   = (const float*)d_in[7];
    const float* mlp_W2   = (const float*)d_in[8];
    const float* mlp_b2   = (const float*)d_in[9];
    const float* root_W   = (const float*)d_in[10];
    const float* conv_b   = (const float*)d_in[11];
    const float* gWih     = (const float*)d_in[12];
    const float* gWhh     = (const float*)d_in[13];
    const float* gbih     = (const float*)d_in[14];
    const float* gbhh     = (const float*)d_in[15];
    const float* lWih     = (const float*)d_in[16];
    const float* lWhh     = (const float*)d_in[17];
    const float* lbih     = (const float*)d_in[18];
    const float* lbhh     = (const float*)d_in[19];
    const float* lin1_W   = (const float*)d_in[20];
    const float* lin1_b   = (const float*)d_in[21];
    const float* lin2_W   = (const float*)d_in[22];
    const float* lin2_b   = (const float*)d_in[23];
    const int* src = ei;
    const int* dst = ei + NE;
    float* out = (float*)d_out;

    char* w = (char*)d_ws;
    size_t off = 0;
    auto alloc = [&](size_t bytes) -> void* {
        void* p = w + off;
        off = (off + bytes + 255) & ~(size_t)255;
        return p;
    };
    float* deg    = (float*)alloc((size_t)NN * 4);            // 160000 (256-mult)
    float* aggr   = (float*)alloc((size_t)NN * 32 * 4);       // contiguous after deg
    float* h      = (float*)alloc((size_t)NN * 32 * 4);
    halfT* hH     = (halfT*)alloc((size_t)NN * 32 * 2);
    halfT* ehF    = (halfT*)alloc((size_t)NEP * 128 * 2);
    halfT* BfF    = (halfT*)alloc((size_t)129 * 2 * 64 * 8 * 2);
    int*   starts = (int*)alloc((size_t)(NB + 1) * 4);
    float* WgT    = (float*)alloc((size_t)3072 * 4);
    float* WhT    = (float*)alloc((size_t)3072 * 4);
    float* lWihT  = (float*)alloc((size_t)8192 * 4);
    float* lWhhT  = (float*)alloc((size_t)4096 * 4);
    float* lin1T  = (float*)alloc((size_t)2048 * 4);
    if (ws_size < off) return;   // cannot run

    // one memset covers deg + aggr (contiguous)
    hipMemsetAsync(deg, 0, (size_t)NN * 4 + (size_t)NN * 32 * 4, stream);

    k_setup<<<56035, 256, 0, stream>>>(x, lin0_W, lin0_b, ea, mlp_W1, mlp_b1,
        mlp_W2, mlp_b2, dst, gWih, gWhh, lWih, lWhh, lin1_W,
        h, hH, ehF, BfF, deg, WgT, WhT, lWihT, lWhhT, lin1T);
    k_starts<<<5, 256, 0, stream>>>(batch, starts);

    for (int t = 0; t < 3; t++){
        k_msg3<<<NEP / 128, 256, 0, stream>>>(ehF, BfF, hH, src, dst, aggr);
        k_gru<<<NN / 8, 256, 0, stream>>>(aggr, deg, h, hH, root_W, conv_b,
                                          WgT, WhT, gbih, gbhh);
    }
    k_s2s<<<NB, 64, 0, stream>>>(h, starts, lWihT, lWhhT, lbih, lbhh,
                                 lin1T, lin1_b, lin2_W, lin2_b, out);
}

// Round 8
// 399.486 us; speedup vs baseline: 2.4441x; 1.1328x over previous
//
#include <hip/hip_runtime.h>
#include <hip/hip_bf16.h>
#include <cstdint>

#define NN 40000
#define NE 100000
#define NEP 100096           // 32-aligned edge count
#define NB 1024

typedef _Float16 halfT;
typedef _Float16 half8 __attribute__((ext_vector_type(8)));
typedef float f32x4 __attribute__((ext_vector_type(4)));

static __device__ __forceinline__ float sigf(float x){ return 1.f/(1.f + expf(-x)); }

// =====================================================================
// k_setup: one kernel, 6 block-ranges (all vectorized)
//  R0 [0,1250):       h = relu(x@lin0^T+b): 4 outputs/thread, lin0_W in LDS
//  R1 [1250,7506):    ehF fp16 fragment-order: 8 outputs/thread, W1 in LDS
//  R2 [7506,8022):    BfF: W2 repacked into B-fragment stream
//  R3 [8022,8413):    deg atomics
//  R4 [8413,8493):    weight transposes for gru/s2s
//  R5 [8493,8498):    starts[g] = lower_bound(batch, g)
// ehF layout:  ehF[(((g16*4+s)*64 + m*4+q))*8 + i] = eh[g16*16+m][32s+q*8+i]
// BfF layout:  BfF[(((ks*2+nt)*64 + m*4+q))*8 + i] =
//                ks<128 : W2[(ks>>2)*32 + nt*16+m][32*(ks&3)+q*8+i]
//                ks==128: b2[(q*8+i)*32 + nt*16+m]          (bias K-tile)
// =====================================================================
__global__ __launch_bounds__(256) void k_setup(
    const float* __restrict__ x, const float* __restrict__ lin0_W, const float* __restrict__ lin0_b,
    const float* __restrict__ ea, const float* __restrict__ W1, const float* __restrict__ b1,
    const float* __restrict__ W2, const float* __restrict__ b2,
    const int* __restrict__ dstA, const int* __restrict__ batch,
    const float* __restrict__ gWih, const float* __restrict__ gWhh,
    const float* __restrict__ lWih, const float* __restrict__ lWhh, const float* __restrict__ lin1_W,
    float* __restrict__ h, halfT* __restrict__ hH, halfT* __restrict__ ehF, halfT* __restrict__ BfF,
    float* __restrict__ deg, float* __restrict__ WgT, float* __restrict__ WhT,
    float* __restrict__ lWihT, float* __restrict__ lWhhT, float* __restrict__ lin1T,
    int* __restrict__ starts)
{
    int b = blockIdx.x, tid = threadIdx.x;
    if (b < 1250){
        __shared__ float sW[32 * 30];
        __shared__ float sB[32];
        for (int idx = tid; idx < 960; idx += 256) sW[idx] = lin0_W[idx];
        if (tid < 32) sB[tid] = lin0_b[tid];
        __syncthreads();
        int t8 = b * 256 + tid;             // [0, NN*8)
        int i = t8 >> 3, q4 = t8 & 7;       // node, channel-quad
        const float* xr = x + (size_t)i * 30;
        float xv[30];
        #pragma unroll
        for (int f = 0; f < 30; f++) xv[f] = xr[f];
        float r[4];
        #pragma unroll
        for (int cc = 0; cc < 4; cc++){
            int c = q4 * 4 + cc;
            const float* wr = &sW[c * 30];
            float s = sB[c];
            #pragma unroll
            for (int f = 0; f < 30; f++) s += xv[f] * wr[f];
            r[cc] = fmaxf(s, 0.f);
        }
        *(float4*)(h + (size_t)i * 32 + q4 * 4) = *(float4*)r;
        halfT rh[4];
        #pragma unroll
        for (int cc = 0; cc < 4; cc++) rh[cc] = (halfT)r[cc];
        *(uint2*)(hH + (size_t)i * 32 + q4 * 4) = *(uint2*)rh;
    } else if (b < 7506){
        __shared__ float sW1[128 * 11];
        __shared__ float sb1[128];
        for (int idx = tid; idx < 1408; idx += 256) sW1[idx] = W1[idx];
        if (tid < 128) sb1[tid] = b1[tid];
        __syncthreads();
        int t8 = (b - 1250) * 256 + tid;    // [0, NEP*16)
        int ch = t8 & 63;
        int s4 = (t8 >> 6) & 3;
        int g16 = t8 >> 8;
        int m = ch >> 2, q = ch & 3;
        int e = g16 * 16 + m;
        int kb = 32 * s4 + q * 8;
        halfT v[8];
        if (e < NE){
            const float* xr = ea + (size_t)e * 11;
            float xv[11];
            #pragma unroll
            for (int f = 0; f < 11; f++) xv[f] = xr[f];
            #pragma unroll
            for (int i8 = 0; i8 < 8; i8++){
                int k = kb + i8;
                const float* wr = &sW1[k * 11];
                float s = sb1[k];
                #pragma unroll
                for (int f = 0; f < 11; f++) s += xv[f] * wr[f];
                v[i8] = (halfT)fmaxf(s, 0.f);
            }
        } else {
            #pragma unroll
            for (int i8 = 0; i8 < 8; i8++) v[i8] = (halfT)0.f;
        }
        *(half8*)(ehF + (size_t)t8 * 8) = *(half8*)v;
    } else if (b < 8022){
        int gid = (b - 7506) * 256 + tid;   // 129*2*64*8 = 132096
        int i8 = gid & 7;
        int ch = (gid >> 3) & 63;
        int nt = (gid >> 9) & 1;
        int ks = gid >> 10;
        int m = ch >> 2, q = ch & 3;
        int o = nt * 16 + m;
        float v;
        if (ks < 128){
            int c = ks >> 2;
            int k = 32 * (ks & 3) + q * 8 + i8;
            v = W2[(size_t)(c * 32 + o) * 128 + k];
        } else {
            int c = q * 8 + i8;
            v = b2[c * 32 + o];
        }
        BfF[gid] = (halfT)v;
    } else if (b < 8413){
        int e = (b - 8022) * 256 + tid;
        if (e < NE) atomicAdd(&deg[dstA[e]], 1.f);
    } else if (b < 8493){
        int t = (b - 8413) * 256 + tid;     // 20480
        if (t < 3072){ int k = t / 96, j = t % 96; WgT[t] = gWih[(size_t)j * 32 + k]; }
        else if (t < 6144){ int t2 = t - 3072; int k = t2 / 96, j = t2 % 96; WhT[t2] = gWhh[(size_t)j * 32 + k]; }
        else if (t < 14336){ int t2 = t - 6144; int k = t2 >> 7, j = t2 & 127; lWihT[t2] = lWih[(size_t)j * 64 + k]; }
        else if (t < 18432){ int t2 = t - 14336; int k = t2 >> 7, j = t2 & 127; lWhhT[t2] = lWhh[(size_t)j * 32 + k]; }
        else { int t2 = t - 18432; int k = t2 >> 5, c = t2 & 31; lin1T[t2] = lin1_W[(size_t)c * 64 + k]; }
    } else {
        int g = (b - 8493) * 256 + tid;
        if (g > NB) return;
        int lo = 0, hi = NN;
        while (lo < hi){
            int mid = (lo + hi) >> 1;
            if (batch[mid] < g) lo = mid + 1; else hi = mid;
        }
        starts[g] = lo;
    }
}

// =====================================================================
// k_msg3: NNConv message pass as a K=4096(+32 bias) GEMM with on-the-fly
// A = u[e][c]*eh[e][k]. One wave = 32 edges (two 16-edge A-rows), N=32 (2 tiles).
// No LDS, no barriers. MFMA conventions identical to round-3-verified kernel:
//   A-frag: row = l&15, k-slot = (l>>4)*8+i ; B-frag: col(o) = l&15, same k-slot;
//   D: row = (l>>4)*4+r (A-row), col = l&15 (B-col).
// =====================================================================
__global__ __launch_bounds__(256) void k_msg3(
    const halfT* __restrict__ ehF, const halfT* __restrict__ BfF,
    const halfT* __restrict__ hH,
    const int* __restrict__ src, const int* __restrict__ dst,
    float* __restrict__ aggr)
{
    int wid = (blockIdx.x * 256 + threadIdx.x) >> 6;
    int l = threadIdx.x & 63;
    int m = l & 15, q = l >> 4;
    int eb = wid * 32;
    half8 u0[4], u1[4], ub0, ub1;
    {
        int e0 = eb + m;      int se0 = (e0 < NE) ? src[e0] : 0;
        int e1 = eb + 16 + m; int se1 = (e1 < NE) ? src[e1] : 0;
        const halfT* p0 = hH + (size_t)se0 * 32;
        const halfT* p1 = hH + (size_t)se1 * 32;
        #pragma unroll
        for (int j = 0; j < 4; j++){
            u0[j] = *(const half8*)(p0 + j * 8);
            u1[j] = *(const half8*)(p1 + j * 8);
        }
        ub0 = *(const half8*)(p0 + q * 8);
        ub1 = *(const half8*)(p1 + q * 8);
    }
    half8 eh0[4], eh1[4];
    {
        int g0 = eb >> 4;
        #pragma unroll
        for (int s = 0; s < 4; s++){
            eh0[s] = *(const half8*)(ehF + ((size_t)(g0 * 4 + s) * 64 + (m * 4 + q)) * 8);
            eh1[s] = *(const half8*)(ehF + ((size_t)((g0 + 1) * 4 + s) * 64 + (m * 4 + q)) * 8);
        }
    }
    f32x4 acc00 = {0,0,0,0}, acc01 = {0,0,0,0}, acc10 = {0,0,0,0}, acc11 = {0,0,0,0};
    const halfT* bbase = BfF + (size_t)(m * 4 + q) * 8;
    #pragma unroll
    for (int ks = 0; ks < 128; ks++){
        half8 b0 = *(const half8*)(bbase + (size_t)(ks * 2 + 0) * 512);
        half8 b1 = *(const half8*)(bbase + (size_t)(ks * 2 + 1) * 512);
        const int c = ks >> 2, s = ks & 3;
        halfT uc0 = u0[c >> 3][c & 7];
        halfT uc1 = u1[c >> 3][c & 7];
        half8 a0 = eh0[s] * uc0;
        half8 a1 = eh1[s] * uc1;
        acc00 = __builtin_amdgcn_mfma_f32_16x16x32_f16(a0, b0, acc00, 0, 0, 0);
        acc01 = __builtin_amdgcn_mfma_f32_16x16x32_f16(a0, b1, acc01, 0, 0, 0);
        acc10 = __builtin_amdgcn_mfma_f32_16x16x32_f16(a1, b0, acc10, 0, 0, 0);
        acc11 = __builtin_amdgcn_mfma_f32_16x16x32_f16(a1, b1, acc11, 0, 0, 0);
    }
    {
        half8 b0 = *(const half8*)(bbase + (size_t)256 * 512);
        half8 b1 = *(const half8*)(bbase + (size_t)257 * 512);
        acc00 = __builtin_amdgcn_mfma_f32_16x16x32_f16(ub0, b0, acc00, 0, 0, 0);
        acc01 = __builtin_amdgcn_mfma_f32_16x16x32_f16(ub0, b1, acc01, 0, 0, 0);
        acc10 = __builtin_amdgcn_mfma_f32_16x16x32_f16(ub1, b0, acc10, 0, 0, 0);
        acc11 = __builtin_amdgcn_mfma_f32_16x16x32_f16(ub1, b1, acc11, 0, 0, 0);
    }
    #pragma unroll
    for (int r = 0; r < 4; r++){
        int ea0 = eb + q * 4 + r;
        if (ea0 < NE){
            int d = dst[ea0];
            atomicAdd(&aggr[(size_t)d * 32 + m],      acc00[r]);
            atomicAdd(&aggr[(size_t)d * 32 + 16 + m], acc01[r]);
        }
        int ea1 = eb + 16 + q * 4 + r;
        if (ea1 < NE){
            int d = dst[ea1];
            atomicAdd(&aggr[(size_t)d * 32 + m],      acc10[r]);
            atomicAdd(&aggr[(size_t)d * 32 + 16 + m], acc11[r]);
        }
    }
}

// =====================================================================
// k_gru: wave-parallel (lane = output channel, 32 lanes per node).
// Consumes aggr and re-zeroes it for the next iteration. Writes h + hH.
// =====================================================================
__global__ __launch_bounds__(256) void k_gru(
    float* __restrict__ aggr, const float* __restrict__ deg, float* __restrict__ h,
    halfT* __restrict__ hH,
    const float* __restrict__ rootW, const float* __restrict__ cb,
    const float* __restrict__ WgT, const float* __restrict__ WhT,
    const float* __restrict__ gbih, const float* __restrict__ gbhh)
{
    int tid = threadIdx.x;
    int i = blockIdx.x * 8 + (tid >> 5);
    int c = tid & 31;
    size_t base = (size_t)i * 32 + c;
    float hq = h[base];
    float av = aggr[base];
    aggr[base] = 0.f;
    float invd = 1.f / fmaxf(deg[i], 1.f);
    float mv = av * invd + cb[c];
    #pragma unroll 8
    for (int k = 0; k < 32; k++)
        mv += __shfl(hq, k, 32) * rootW[k * 32 + c];
    mv = fmaxf(mv, 0.f);
    float gr = gbih[c],      hr = gbhh[c];
    float gz = gbih[32 + c], hz = gbhh[32 + c];
    float gn = gbih[64 + c], hn = gbhh[64 + c];
    #pragma unroll 4
    for (int k = 0; k < 32; k++){
        float mk = __shfl(mv, k, 32);
        float hk = __shfl(hq, k, 32);
        const float* wg = WgT + k * 96;
        const float* wh = WhT + k * 96;
        gr += mk * wg[c];      hr += hk * wh[c];
        gz += mk * wg[32 + c]; hz += hk * wh[32 + c];
        gn += mk * wg[64 + c]; hn += hk * wh[64 + c];
    }
    float r = sigf(gr + hr);
    float z = sigf(gz + hz);
    float n = tanhf(gn + r * hn);
    float hnew = (1.f - z) * n + z * hq;
    h[base] = hnew;
    hH[base] = (halfT)hnew;
}

// =====================================================================
// k_s2s: entire Set2Set (3x LSTM + attention) + final MLP. One wave per graph.
// =====================================================================
__global__ __launch_bounds__(64) void k_s2s(
    const float* __restrict__ h, const int* __restrict__ starts,
    const float* __restrict__ lWihT, const float* __restrict__ lWhhT,
    const float* __restrict__ lbih, const float* __restrict__ lbhh,
    const float* __restrict__ lin1T, const float* __restrict__ lin1_b,
    const float* __restrict__ lin2W, const float* __restrict__ lin2b,
    float* __restrict__ out)
{
    __shared__ float ebuf[256];
    int g = blockIdx.x, l = threadIdx.x;
    int s0 = starts[g], s1 = starts[g + 1];
    int c = l & 31, grp = l >> 5;
    float qs = 0.f, hsv = 0.f, csv = 0.f;
    for (int t = 0; t < 3; t++){
        float a1 = lbih[l] + lbhh[l];
        float a2 = lbih[l + 64] + lbhh[l + 64];
        #pragma unroll 8
        for (int k = 0; k < 64; k++){
            float qk = __shfl(qs, k);
            a1 += qk * lWihT[k * 128 + l];
            a2 += qk * lWihT[k * 128 + 64 + l];
        }
        #pragma unroll 8
        for (int k = 0; k < 32; k++){
            float hk = __shfl(qs, k);
            a1 += hk * lWhhT[k * 128 + l];
            a2 += hk * lWhhT[k * 128 + 64 + l];
        }
        float gate1 = sigf(a1);
        float gate2 = (l < 32) ? tanhf(a2) : sigf(a2);
        float fv = __shfl(gate1, c + 32);
        float ov = __shfl(gate2, c + 32);
        if (l < 32){
            csv = fv * csv + gate1 * gate2;
            hsv = ov * tanhf(csv);
        }
        float hq = __shfl(hsv, c);
        float mx = -3.4e38f;
        for (int idx = s0 + grp; idx < s1; idx += 2){
            float p = h[(size_t)idx * 32 + c] * hq;
            p += __shfl_xor(p, 1);  p += __shfl_xor(p, 2);
            p += __shfl_xor(p, 4);  p += __shfl_xor(p, 8);
            p += __shfl_xor(p, 16);
            int ii = idx - s0;
            if (c == 0 && ii < 256) ebuf[ii] = p;
            mx = fmaxf(mx, p);
        }
        mx = fmaxf(mx, __shfl_xor(mx, 32));
        __syncthreads();
        int n = s1 - s0;
        int nc = n < 256 ? n : 256;
        float ss = 0.f;
        for (int ii = l; ii < nc; ii += 64) ss += expf(ebuf[ii] - mx);
        for (int idx = s0 + 256 + grp; idx < s1; idx += 2){
            float p = h[(size_t)idx * 32 + c] * hq;
            p += __shfl_xor(p, 1);  p += __shfl_xor(p, 2);
            p += __shfl_xor(p, 4);  p += __shfl_xor(p, 8);
            p += __shfl_xor(p, 16);
            if (c == 0) ss += expf(p - mx);
        }
        ss += __shfl_xor(ss, 1);  ss += __shfl_xor(ss, 2);
        ss += __shfl_xor(ss, 4);  ss += __shfl_xor(ss, 8);
        ss += __shfl_xor(ss, 16); ss += __shfl_xor(ss, 32);
        float inv = (ss > 0.f) ? 1.f / ss : 0.f;
        float acc = 0.f;
        for (int idx = s0 + grp; idx < s1; idx += 2){
            int ii = idx - s0;
            float p;
            if (ii < 256) p = ebuf[ii];
            else {
                p = h[(size_t)idx * 32 + c] * hq;
                p += __shfl_xor(p, 1);  p += __shfl_xor(p, 2);
                p += __shfl_xor(p, 4);  p += __shfl_xor(p, 8);
                p += __shfl_xor(p, 16);
            }
            float a = expf(p - mx) * inv;
            acc += a * h[(size_t)idx * 32 + c];
        }
        acc += __shfl_xor(acc, 32);
        qs = (l < 32) ? hsv : acc;
        __syncthreads();
    }
    float s = lin1_b[c];
    #pragma unroll 8
    for (int k = 0; k < 64; k++){
        float qk = __shfl(qs, k);
        s += qk * lin1T[k * 32 + c];
    }
    float pp = (l < 32) ? fmaxf(s, 0.f) * lin2W[c] : 0.f;
    pp += __shfl_xor(pp, 1);  pp += __shfl_xor(pp, 2);
    pp += __shfl_xor(pp, 4);  pp += __shfl_xor(pp, 8);
    pp += __shfl_xor(pp, 16); pp += __shfl_xor(pp, 32);
    if (l == 0) out[g] = pp + lin2b[0];
}

extern "C" void kernel_launch(void* const* d_in, const int* in_sizes, int n_in,
                              void* d_out, int out_size, void* d_ws, size_t ws_size,
                              hipStream_t stream){
    (void)in_sizes; (void)n_in; (void)out_size;
    const float* x        = (const float*)d_in[0];
    const float* ea       = (const float*)d_in[1];
    const int*   ei       = (const int*)d_in[2];
    const int*   batch    = (const int*)d_in[3];
    const float* lin0_W   = (const float*)d_in[4];
    const float* lin0_b   = (const float*)d_in[5];
    const float* mlp_W1   = (const float*)d_in[6];
    const float* mlp_b1   = (const float*)d_in[7];
    const float* mlp_W2   = (const float*)d_in[8];
    const float* mlp_b2   = (const float*)d_in[9];
    const float* root_W   = (const float*)d_in[10];
    const float* conv_b   = (const float*)d_in[11];
    const float* gWih     = (const float*)d_in[12];
    const float* gWhh     = (const float*)d_in[13];
    const float* gbih     = (const float*)d_in[14];
    const float* gbhh     = (const float*)d_in[15];
    const float* lWih     = (const float*)d_in[16];
    const float* lWhh     = (const float*)d_in[17];
    const float* lbih     = (const float*)d_in[18];
    const float* lbhh     = (const float*)d_in[19];
    const float* lin1_W   = (const float*)d_in[20];
    const float* lin1_b   = (const float*)d_in[21];
    const float* lin2_W   = (const float*)d_in[22];
    const float* lin2_b   = (const float*)d_in[23];
    const int* src = ei;
    const int* dst = ei + NE;
    float* out = (float*)d_out;

    char* w = (char*)d_ws;
    size_t off = 0;
    auto alloc = [&](size_t bytes) -> void* {
        void* p = w + off;
        off = (off + bytes + 255) & ~(size_t)255;
        return p;
    };
    float* deg    = (float*)alloc((size_t)NN * 4);            // contiguous with aggr
    float* aggr   = (float*)alloc((size_t)NN * 32 * 4);
    float* h      = (float*)alloc((size_t)NN * 32 * 4);
    halfT* hH     = (halfT*)alloc((size_t)NN * 32 * 2);
    halfT* ehF    = (halfT*)alloc((size_t)NEP * 128 * 2);
    halfT* BfF    = (halfT*)alloc((size_t)129 * 2 * 64 * 8 * 2);
    int*   starts = (int*)alloc((size_t)(NB + 1) * 4);
    float* WgT    = (float*)alloc((size_t)3072 * 4);
    float* WhT    = (float*)alloc((size_t)3072 * 4);
    float* lWihT  = (float*)alloc((size_t)8192 * 4);
    float* lWhhT  = (float*)alloc((size_t)4096 * 4);
    float* lin1T  = (float*)alloc((size_t)2048 * 4);
    if (ws_size < off) return;   // cannot run

    hipMemsetAsync(deg, 0, (size_t)NN * 4 + (size_t)NN * 32 * 4, stream);

    k_setup<<<8498, 256, 0, stream>>>(x, lin0_W, lin0_b, ea, mlp_W1, mlp_b1,
        mlp_W2, mlp_b2, dst, batch, gWih, gWhh, lWih, lWhh, lin1_W,
        h, hH, ehF, BfF, deg, WgT, WhT, lWihT, lWhhT, lin1T, starts);

    for (int t = 0; t < 3; t++){
        k_msg3<<<NEP / 128, 256, 0, stream>>>(ehF, BfF, hH, src, dst, aggr);
        k_gru<<<NN / 8, 256, 0, stream>>>(aggr, deg, h, hH, root_W, conv_b,
                                          WgT, WhT, gbih, gbhh);
    }
    k_s2s<<<NB, 64, 0, stream>>>(h, starts, lWihT, lWhhT, lbih, lbhh,
                                 lin1T, lin1_b, lin2_W, lin2_b, out);
}

// Round 9
// 398.331 us; speedup vs baseline: 2.4511x; 1.0029x over previous
//
#include <hip/hip_runtime.h>
#include <hip/hip_bf16.h>
#include <cstdint>

#define NN 40000
#define NE 100000
#define NEP 100096           // 32-aligned edge count
#define NB 1024

typedef _Float16 halfT;
typedef _Float16 half8 __attribute__((ext_vector_type(8)));
typedef float f32x4 __attribute__((ext_vector_type(4)));

static __device__ __forceinline__ float sigf(float x){ return 1.f/(1.f + expf(-x)); }

// =====================================================================
// k_setup: one kernel, 6 block-ranges (all vectorized)  [unchanged from R8]
// =====================================================================
__global__ __launch_bounds__(256) void k_setup(
    const float* __restrict__ x, const float* __restrict__ lin0_W, const float* __restrict__ lin0_b,
    const float* __restrict__ ea, const float* __restrict__ W1, const float* __restrict__ b1,
    const float* __restrict__ W2, const float* __restrict__ b2,
    const int* __restrict__ dstA, const int* __restrict__ batch,
    const float* __restrict__ gWih, const float* __restrict__ gWhh,
    const float* __restrict__ lWih, const float* __restrict__ lWhh, const float* __restrict__ lin1_W,
    float* __restrict__ h, halfT* __restrict__ hH, halfT* __restrict__ ehF, halfT* __restrict__ BfF,
    float* __restrict__ deg, float* __restrict__ WgT, float* __restrict__ WhT,
    float* __restrict__ lWihT, float* __restrict__ lWhhT, float* __restrict__ lin1T,
    int* __restrict__ starts)
{
    int b = blockIdx.x, tid = threadIdx.x;
    if (b < 1250){
        __shared__ float sW[32 * 30];
        __shared__ float sB[32];
        for (int idx = tid; idx < 960; idx += 256) sW[idx] = lin0_W[idx];
        if (tid < 32) sB[tid] = lin0_b[tid];
        __syncthreads();
        int t8 = b * 256 + tid;             // [0, NN*8)
        int i = t8 >> 3, q4 = t8 & 7;       // node, channel-quad
        const float* xr = x + (size_t)i * 30;
        float xv[30];
        #pragma unroll
        for (int f = 0; f < 30; f++) xv[f] = xr[f];
        float r[4];
        #pragma unroll
        for (int cc = 0; cc < 4; cc++){
            int c = q4 * 4 + cc;
            const float* wr = &sW[c * 30];
            float s = sB[c];
            #pragma unroll
            for (int f = 0; f < 30; f++) s += xv[f] * wr[f];
            r[cc] = fmaxf(s, 0.f);
        }
        *(float4*)(h + (size_t)i * 32 + q4 * 4) = *(float4*)r;
        halfT rh[4];
        #pragma unroll
        for (int cc = 0; cc < 4; cc++) rh[cc] = (halfT)r[cc];
        *(uint2*)(hH + (size_t)i * 32 + q4 * 4) = *(uint2*)rh;
    } else if (b < 7506){
        __shared__ float sW1[128 * 11];
        __shared__ float sb1[128];
        for (int idx = tid; idx < 1408; idx += 256) sW1[idx] = W1[idx];
        if (tid < 128) sb1[tid] = b1[tid];
        __syncthreads();
        int t8 = (b - 1250) * 256 + tid;    // [0, NEP*16)
        int ch = t8 & 63;
        int s4 = (t8 >> 6) & 3;
        int g16 = t8 >> 8;
        int m = ch >> 2, q = ch & 3;
        int e = g16 * 16 + m;
        int kb = 32 * s4 + q * 8;
        halfT v[8];
        if (e < NE){
            const float* xr = ea + (size_t)e * 11;
            float xv[11];
            #pragma unroll
            for (int f = 0; f < 11; f++) xv[f] = xr[f];
            #pragma unroll
            for (int i8 = 0; i8 < 8; i8++){
                int k = kb + i8;
                const float* wr = &sW1[k * 11];
                float s = sb1[k];
                #pragma unroll
                for (int f = 0; f < 11; f++) s += xv[f] * wr[f];
                v[i8] = (halfT)fmaxf(s, 0.f);
            }
        } else {
            #pragma unroll
            for (int i8 = 0; i8 < 8; i8++) v[i8] = (halfT)0.f;
        }
        *(half8*)(ehF + (size_t)t8 * 8) = *(half8*)v;
    } else if (b < 8022){
        int gid = (b - 7506) * 256 + tid;   // 129*2*64*8 = 132096
        int i8 = gid & 7;
        int ch = (gid >> 3) & 63;
        int nt = (gid >> 9) & 1;
        int ks = gid >> 10;
        int m = ch >> 2, q = ch & 3;
        int o = nt * 16 + m;
        float v;
        if (ks < 128){
            int c = ks >> 2;
            int k = 32 * (ks & 3) + q * 8 + i8;
            v = W2[(size_t)(c * 32 + o) * 128 + k];
        } else {
            int c = q * 8 + i8;
            v = b2[c * 32 + o];
        }
        BfF[gid] = (halfT)v;
    } else if (b < 8413){
        int e = (b - 8022) * 256 + tid;
        if (e < NE) atomicAdd(&deg[dstA[e]], 1.f);
    } else if (b < 8493){
        int t = (b - 8413) * 256 + tid;     // 20480
        if (t < 3072){ int k = t / 96, j = t % 96; WgT[t] = gWih[(size_t)j * 32 + k]; }
        else if (t < 6144){ int t2 = t - 3072; int k = t2 / 96, j = t2 % 96; WhT[t2] = gWhh[(size_t)j * 32 + k]; }
        else if (t < 14336){ int t2 = t - 6144; int k = t2 >> 7, j = t2 & 127; lWihT[t2] = lWih[(size_t)j * 64 + k]; }
        else if (t < 18432){ int t2 = t - 14336; int k = t2 >> 7, j = t2 & 127; lWhhT[t2] = lWhh[(size_t)j * 32 + k]; }
        else { int t2 = t - 18432; int k = t2 >> 5, c = t2 & 31; lin1T[t2] = lin1_W[(size_t)c * 64 + k]; }
    } else {
        int g = (b - 8493) * 256 + tid;
        if (g > NB) return;
        int lo = 0, hi = NN;
        while (lo < hi){
            int mid = (lo + hi) >> 1;
            if (batch[mid] < g) lo = mid + 1; else hi = mid;
        }
        starts[g] = lo;
    }
}

// =====================================================================
// k_msg3: NNConv message pass as a K=4096(+32 bias) GEMM with on-the-fly
// A = u[e][c]*eh[e][k]. One wave = 32 edges, N=32 (2 tiles), full K.
// R9 change: __launch_bounds__(256,2) + 8-deep grouped B-loads (16
// independent global loads in flight) to fix MLP starvation at 3 waves/SIMD.
// MFMA conventions identical to round-3-verified kernel.
// =====================================================================
__global__ __launch_bounds__(256, 2) void k_msg3(
    const halfT* __restrict__ ehF, const halfT* __restrict__ BfF,
    const halfT* __restrict__ hH,
    const int* __restrict__ src, const int* __restrict__ dst,
    float* __restrict__ aggr)
{
    int wid = (blockIdx.x * 256 + threadIdx.x) >> 6;
    int l = threadIdx.x & 63;
    int m = l & 15, q = l >> 4;
    int eb = wid * 32;
    half8 u0[4], u1[4], ub0, ub1;
    {
        int e0 = eb + m;      int se0 = (e0 < NE) ? src[e0] : 0;
        int e1 = eb + 16 + m; int se1 = (e1 < NE) ? src[e1] : 0;
        const halfT* p0 = hH + (size_t)se0 * 32;
        const halfT* p1 = hH + (size_t)se1 * 32;
        #pragma unroll
        for (int j = 0; j < 4; j++){
            u0[j] = *(const half8*)(p0 + j * 8);
            u1[j] = *(const half8*)(p1 + j * 8);
        }
        ub0 = *(const half8*)(p0 + q * 8);
        ub1 = *(const half8*)(p1 + q * 8);
    }
    half8 eh0[4], eh1[4];
    {
        int g0 = eb >> 4;
        #pragma unroll
        for (int s = 0; s < 4; s++){
            eh0[s] = *(const half8*)(ehF + ((size_t)(g0 * 4 + s) * 64 + (m * 4 + q)) * 8);
            eh1[s] = *(const half8*)(ehF + ((size_t)((g0 + 1) * 4 + s) * 64 + (m * 4 + q)) * 8);
        }
    }
    f32x4 acc00 = {0,0,0,0}, acc01 = {0,0,0,0}, acc10 = {0,0,0,0}, acc11 = {0,0,0,0};
    const halfT* bbase = BfF + (size_t)(m * 4 + q) * 8;
    #pragma unroll
    for (int kg = 0; kg < 16; kg++){
        // group-load: 16 independent B-loads in flight before any consume
        half8 b[8][2];
        #pragma unroll
        for (int j = 0; j < 8; j++){
            b[j][0] = *(const half8*)(bbase + (size_t)((kg * 8 + j) * 2 + 0) * 512);
            b[j][1] = *(const half8*)(bbase + (size_t)((kg * 8 + j) * 2 + 1) * 512);
        }
        #pragma unroll
        for (int j = 0; j < 8; j++){
            const int ks = kg * 8 + j;
            const int c = ks >> 2, s = ks & 3;
            halfT uc0 = u0[c >> 3][c & 7];
            halfT uc1 = u1[c >> 3][c & 7];
            half8 a0 = eh0[s] * uc0;
            half8 a1 = eh1[s] * uc1;
            acc00 = __builtin_amdgcn_mfma_f32_16x16x32_f16(a0, b[j][0], acc00, 0, 0, 0);
            acc01 = __builtin_amdgcn_mfma_f32_16x16x32_f16(a0, b[j][1], acc01, 0, 0, 0);
            acc10 = __builtin_amdgcn_mfma_f32_16x16x32_f16(a1, b[j][0], acc10, 0, 0, 0);
            acc11 = __builtin_amdgcn_mfma_f32_16x16x32_f16(a1, b[j][1], acc11, 0, 0, 0);
        }
    }
    {   // bias K-tile (ks = 128)
        half8 b0 = *(const half8*)(bbase + (size_t)256 * 512);
        half8 b1 = *(const half8*)(bbase + (size_t)257 * 512);
        acc00 = __builtin_amdgcn_mfma_f32_16x16x32_f16(ub0, b0, acc00, 0, 0, 0);
        acc01 = __builtin_amdgcn_mfma_f32_16x16x32_f16(ub0, b1, acc01, 0, 0, 0);
        acc10 = __builtin_amdgcn_mfma_f32_16x16x32_f16(ub1, b0, acc10, 0, 0, 0);
        acc11 = __builtin_amdgcn_mfma_f32_16x16x32_f16(ub1, b1, acc11, 0, 0, 0);
    }
    #pragma unroll
    for (int r = 0; r < 4; r++){
        int ea0 = eb + q * 4 + r;
        if (ea0 < NE){
            int d = dst[ea0];
            atomicAdd(&aggr[(size_t)d * 32 + m],      acc00[r]);
            atomicAdd(&aggr[(size_t)d * 32 + 16 + m], acc01[r]);
        }
        int ea1 = eb + 16 + q * 4 + r;
        if (ea1 < NE){
            int d = dst[ea1];
            atomicAdd(&aggr[(size_t)d * 32 + m],      acc10[r]);
            atomicAdd(&aggr[(size_t)d * 32 + 16 + m], acc11[r]);
        }
    }
}

// =====================================================================
// k_gru: wave-parallel (lane = output channel, 32 lanes per node).  [unchanged]
// =====================================================================
__global__ __launch_bounds__(256) void k_gru(
    float* __restrict__ aggr, const float* __restrict__ deg, float* __restrict__ h,
    halfT* __restrict__ hH,
    const float* __restrict__ rootW, const float* __restrict__ cb,
    const float* __restrict__ WgT, const float* __restrict__ WhT,
    const float* __restrict__ gbih, const float* __restrict__ gbhh)
{
    int tid = threadIdx.x;
    int i = blockIdx.x * 8 + (tid >> 5);
    int c = tid & 31;
    size_t base = (size_t)i * 32 + c;
    float hq = h[base];
    float av = aggr[base];
    aggr[base] = 0.f;
    float invd = 1.f / fmaxf(deg[i], 1.f);
    float mv = av * invd + cb[c];
    #pragma unroll 8
    for (int k = 0; k < 32; k++)
        mv += __shfl(hq, k, 32) * rootW[k * 32 + c];
    mv = fmaxf(mv, 0.f);
    float gr = gbih[c],      hr = gbhh[c];
    float gz = gbih[32 + c], hz = gbhh[32 + c];
    float gn = gbih[64 + c], hn = gbhh[64 + c];
    #pragma unroll 4
    for (int k = 0; k < 32; k++){
        float mk = __shfl(mv, k, 32);
        float hk = __shfl(hq, k, 32);
        const float* wg = WgT + k * 96;
        const float* wh = WhT + k * 96;
        gr += mk * wg[c];      hr += hk * wh[c];
        gz += mk * wg[32 + c]; hz += hk * wh[32 + c];
        gn += mk * wg[64 + c]; hn += hk * wh[64 + c];
    }
    float r = sigf(gr + hr);
    float z = sigf(gz + hz);
    float n = tanhf(gn + r * hn);
    float hnew = (1.f - z) * n + z * hq;
    h[base] = hnew;
    hH[base] = (halfT)hnew;
}

// =====================================================================
// k_s2s: entire Set2Set (3x LSTM + attention) + final MLP.  [unchanged]
// =====================================================================
__global__ __launch_bounds__(64) void k_s2s(
    const float* __restrict__ h, const int* __restrict__ starts,
    const float* __restrict__ lWihT, const float* __restrict__ lWhhT,
    const float* __restrict__ lbih, const float* __restrict__ lbhh,
    const float* __restrict__ lin1T, const float* __restrict__ lin1_b,
    const float* __restrict__ lin2W, const float* __restrict__ lin2b,
    float* __restrict__ out)
{
    __shared__ float ebuf[256];
    int g = blockIdx.x, l = threadIdx.x;
    int s0 = starts[g], s1 = starts[g + 1];
    int c = l & 31, grp = l >> 5;
    float qs = 0.f, hsv = 0.f, csv = 0.f;
    for (int t = 0; t < 3; t++){
        float a1 = lbih[l] + lbhh[l];
        float a2 = lbih[l + 64] + lbhh[l + 64];
        #pragma unroll 8
        for (int k = 0; k < 64; k++){
            float qk = __shfl(qs, k);
            a1 += qk * lWihT[k * 128 + l];
            a2 += qk * lWihT[k * 128 + 64 + l];
        }
        #pragma unroll 8
        for (int k = 0; k < 32; k++){
            float hk = __shfl(qs, k);
            a1 += hk * lWhhT[k * 128 + l];
            a2 += hk * lWhhT[k * 128 + 64 + l];
        }
        float gate1 = sigf(a1);
        float gate2 = (l < 32) ? tanhf(a2) : sigf(a2);
        float fv = __shfl(gate1, c + 32);
        float ov = __shfl(gate2, c + 32);
        if (l < 32){
            csv = fv * csv + gate1 * gate2;
            hsv = ov * tanhf(csv);
        }
        float hq = __shfl(hsv, c);
        float mx = -3.4e38f;
        for (int idx = s0 + grp; idx < s1; idx += 2){
            float p = h[(size_t)idx * 32 + c] * hq;
            p += __shfl_xor(p, 1);  p += __shfl_xor(p, 2);
            p += __shfl_xor(p, 4);  p += __shfl_xor(p, 8);
            p += __shfl_xor(p, 16);
            int ii = idx - s0;
            if (c == 0 && ii < 256) ebuf[ii] = p;
            mx = fmaxf(mx, p);
        }
        mx = fmaxf(mx, __shfl_xor(mx, 32));
        __syncthreads();
        int n = s1 - s0;
        int nc = n < 256 ? n : 256;
        float ss = 0.f;
        for (int ii = l; ii < nc; ii += 64) ss += expf(ebuf[ii] - mx);
        for (int idx = s0 + 256 + grp; idx < s1; idx += 2){
            float p = h[(size_t)idx * 32 + c] * hq;
            p += __shfl_xor(p, 1);  p += __shfl_xor(p, 2);
            p += __shfl_xor(p, 4);  p += __shfl_xor(p, 8);
            p += __shfl_xor(p, 16);
            if (c == 0) ss += expf(p - mx);
        }
        ss += __shfl_xor(ss, 1);  ss += __shfl_xor(ss, 2);
        ss += __shfl_xor(ss, 4);  ss += __shfl_xor(ss, 8);
        ss += __shfl_xor(ss, 16); ss += __shfl_xor(ss, 32);
        float inv = (ss > 0.f) ? 1.f / ss : 0.f;
        float acc = 0.f;
        for (int idx = s0 + grp; idx < s1; idx += 2){
            int ii = idx - s0;
            float p;
            if (ii < 256) p = ebuf[ii];
            else {
                p = h[(size_t)idx * 32 + c] * hq;
                p += __shfl_xor(p, 1);  p += __shfl_xor(p, 2);
                p += __shfl_xor(p, 4);  p += __shfl_xor(p, 8);
                p += __shfl_xor(p, 16);
            }
            float a = expf(p - mx) * inv;
            acc += a * h[(size_t)idx * 32 + c];
        }
        acc += __shfl_xor(acc, 32);
        qs = (l < 32) ? hsv : acc;
        __syncthreads();
    }
    float s = lin1_b[c];
    #pragma unroll 8
    for (int k = 0; k < 64; k++){
        float qk = __shfl(qs, k);
        s += qk * lin1T[k * 32 + c];
    }
    float pp = (l < 32) ? fmaxf(s, 0.f) * lin2W[c] : 0.f;
    pp += __shfl_xor(pp, 1);  pp += __shfl_xor(pp, 2);
    pp += __shfl_xor(pp, 4);  pp += __shfl_xor(pp, 8);
    pp += __shfl_xor(pp, 16); pp += __shfl_xor(pp, 32);
    if (l == 0) out[g] = pp + lin2b[0];
}

extern "C" void kernel_launch(void* const* d_in, const int* in_sizes, int n_in,
                              void* d_out, int out_size, void* d_ws, size_t ws_size,
                              hipStream_t stream){
    (void)in_sizes; (void)n_in; (void)out_size;
    const float* x        = (const float*)d_in[0];
    const float* ea       = (const float*)d_in[1];
    const int*   ei       = (const int*)d_in[2];
    const int*   batch    = (const int*)d_in[3];
    const float* lin0_W   = (const float*)d_in[4];
    const float* lin0_b   = (const float*)d_in[5];
    const float* mlp_W1   = (const float*)d_in[6];
    const float* mlp_b1   = (const float*)d_in[7];
    const float* mlp_W2   = (const float*)d_in[8];
    const float* mlp_b2   = (const float*)d_in[9];
    const float* root_W   = (const float*)d_in[10];
    const float* conv_b   = (const float*)d_in[11];
    const float* gWih     = (const float*)d_in[12];
    const float* gWhh     = (const float*)d_in[13];
    const float* gbih     = (const float*)d_in[14];
    const float* gbhh     = (const float*)d_in[15];
    const float* lWih     = (const float*)d_in[16];
    const float* lWhh     = (const float*)d_in[17];
    const float* lbih     = (const float*)d_in[18];
    const float* lbhh     = (const float*)d_in[19];
    const float* lin1_W   = (const float*)d_in[20];
    const float* lin1_b   = (const float*)d_in[21];
    const float* lin2_W   = (const float*)d_in[22];
    const float* lin2_b   = (const float*)d_in[23];
    const int* src = ei;
    const int* dst = ei + NE;
    float* out = (float*)d_out;

    char* w = (char*)d_ws;
    size_t off = 0;
    auto alloc = [&](size_t bytes) -> void* {
        void* p = w + off;
        off = (off + bytes + 255) & ~(size_t)255;
        return p;
    };
    float* deg    = (float*)alloc((size_t)NN * 4);            // contiguous with aggr
    float* aggr   = (float*)alloc((size_t)NN * 32 * 4);
    float* h      = (float*)alloc((size_t)NN * 32 * 4);
    halfT* hH     = (halfT*)alloc((size_t)NN * 32 * 2);
    halfT* ehF    = (halfT*)alloc((size_t)NEP * 128 * 2);
    halfT* BfF    = (halfT*)alloc((size_t)129 * 2 * 64 * 8 * 2);
    int*   starts = (int*)alloc((size_t)(NB + 1) * 4);
    float* WgT    = (float*)alloc((size_t)3072 * 4);
    float* WhT    = (float*)alloc((size_t)3072 * 4);
    float* lWihT  = (float*)alloc((size_t)8192 * 4);
    float* lWhhT  = (float*)alloc((size_t)4096 * 4);
    float* lin1T  = (float*)alloc((size_t)2048 * 4);
    if (ws_size < off) return;   // cannot run

    hipMemsetAsync(deg, 0, (size_t)NN * 4 + (size_t)NN * 32 * 4, stream);

    k_setup<<<8498, 256, 0, stream>>>(x, lin0_W, lin0_b, ea, mlp_W1, mlp_b1,
        mlp_W2, mlp_b2, dst, batch, gWih, gWhh, lWih, lWhh, lin1_W,
        h, hH, ehF, BfF, deg, WgT, WhT, lWihT, lWhhT, lin1T, starts);

    for (int t = 0; t < 3; t++){
        k_msg3<<<NEP / 128, 256, 0, stream>>>(ehF, BfF, hH, src, dst, aggr);
        k_gru<<<NN / 8, 256, 0, stream>>>(aggr, deg, h, hH, root_W, conv_b,
                                          WgT, WhT, gbih, gbhh);
    }
    k_s2s<<<NB, 64, 0, stream>>>(h, starts, lWihT, lWhhT, lbih, lbhh,
                                 lin1T, lin1_b, lin2_W, lin2_b, out);
}

// Round 10
// 313.396 us; speedup vs baseline: 3.1154x; 1.2710x over previous
//
#include <hip/hip_runtime.h>
#include <hip/hip_bf16.h>
#include <cstdint>

#define NN 40000
#define NE 100000
#define NEP 100096           // 32-aligned edge count
#define NB 1024

typedef _Float16 halfT;
typedef _Float16 half8 __attribute__((ext_vector_type(8)));
typedef float f32x4 __attribute__((ext_vector_type(4)));

static __device__ __forceinline__ float sigf(float x){ return 1.f/(1.f + expf(-x)); }

// =====================================================================
// k_setup: one kernel, 6 block-ranges (all vectorized)
// R9->R10 change: ehF/BfF fragment storage is now LANE-LINEAR
//   (position ch holds the fragment lane l=ch needs: m=ch&15, q=ch>>4)
// so LDS/global fragment reads are linear in lane id (conflict-free).
// ehF layout:  ehF[(((g16*4+s)*64 + l))*8 + i] = eh[g16*16+(l&15)][32s+(l>>4)*8+i]
// BfF layout:  BfF[(((ks*2+nt)*64 + l))*8 + i] =
//                ks<128 : W2[(ks>>2)*32 + nt*16+(l&15)][32*(ks&3)+(l>>4)*8+i]
//                ks==128: b2[((l>>4)*8+i)*32 + nt*16+(l&15)]     (bias K-tile)
// =====================================================================
__global__ __launch_bounds__(256) void k_setup(
    const float* __restrict__ x, const float* __restrict__ lin0_W, const float* __restrict__ lin0_b,
    const float* __restrict__ ea, const float* __restrict__ W1, const float* __restrict__ b1,
    const float* __restrict__ W2, const float* __restrict__ b2,
    const int* __restrict__ dstA, const int* __restrict__ batch,
    const float* __restrict__ gWih, const float* __restrict__ gWhh,
    const float* __restrict__ lWih, const float* __restrict__ lWhh, const float* __restrict__ lin1_W,
    float* __restrict__ h, halfT* __restrict__ hH, halfT* __restrict__ ehF, halfT* __restrict__ BfF,
    float* __restrict__ deg, float* __restrict__ WgT, float* __restrict__ WhT,
    float* __restrict__ lWihT, float* __restrict__ lWhhT, float* __restrict__ lin1T,
    int* __restrict__ starts)
{
    int b = blockIdx.x, tid = threadIdx.x;
    if (b < 1250){
        __shared__ float sW[32 * 30];
        __shared__ float sB[32];
        for (int idx = tid; idx < 960; idx += 256) sW[idx] = lin0_W[idx];
        if (tid < 32) sB[tid] = lin0_b[tid];
        __syncthreads();
        int t8 = b * 256 + tid;             // [0, NN*8)
        int i = t8 >> 3, q4 = t8 & 7;       // node, channel-quad
        const float* xr = x + (size_t)i * 30;
        float xv[30];
        #pragma unroll
        for (int f = 0; f < 30; f++) xv[f] = xr[f];
        float r[4];
        #pragma unroll
        for (int cc = 0; cc < 4; cc++){
            int c = q4 * 4 + cc;
            const float* wr = &sW[c * 30];
            float s = sB[c];
            #pragma unroll
            for (int f = 0; f < 30; f++) s += xv[f] * wr[f];
            r[cc] = fmaxf(s, 0.f);
        }
        *(float4*)(h + (size_t)i * 32 + q4 * 4) = *(float4*)r;
        halfT rh[4];
        #pragma unroll
        for (int cc = 0; cc < 4; cc++) rh[cc] = (halfT)r[cc];
        *(uint2*)(hH + (size_t)i * 32 + q4 * 4) = *(uint2*)rh;
    } else if (b < 7506){
        __shared__ float sW1[128 * 11];
        __shared__ float sb1[128];
        for (int idx = tid; idx < 1408; idx += 256) sW1[idx] = W1[idx];
        if (tid < 128) sb1[tid] = b1[tid];
        __syncthreads();
        int t8 = (b - 1250) * 256 + tid;    // [0, NEP*16)
        int ch = t8 & 63;
        int s4 = (t8 >> 6) & 3;
        int g16 = t8 >> 8;
        int m = ch & 15, q = ch >> 4;       // lane-linear content
        int e = g16 * 16 + m;
        int kb = 32 * s4 + q * 8;
        halfT v[8];
        if (e < NE){
            const float* xr = ea + (size_t)e * 11;
            float xv[11];
            #pragma unroll
            for (int f = 0; f < 11; f++) xv[f] = xr[f];
            #pragma unroll
            for (int i8 = 0; i8 < 8; i8++){
                int k = kb + i8;
                const float* wr = &sW1[k * 11];
                float s = sb1[k];
                #pragma unroll
                for (int f = 0; f < 11; f++) s += xv[f] * wr[f];
                v[i8] = (halfT)fmaxf(s, 0.f);
            }
        } else {
            #pragma unroll
            for (int i8 = 0; i8 < 8; i8++) v[i8] = (halfT)0.f;
        }
        *(half8*)(ehF + (size_t)t8 * 8) = *(half8*)v;
    } else if (b < 8022){
        int gid = (b - 7506) * 256 + tid;   // 129*2*64*8 = 132096
        int i8 = gid & 7;
        int ch = (gid >> 3) & 63;
        int nt = (gid >> 9) & 1;
        int ks = gid >> 10;
        int m = ch & 15, q = ch >> 4;       // lane-linear content
        int o = nt * 16 + m;
        float v;
        if (ks < 128){
            int c = ks >> 2;
            int k = 32 * (ks & 3) + q * 8 + i8;
            v = W2[(size_t)(c * 32 + o) * 128 + k];
        } else {
            int c = q * 8 + i8;
            v = b2[c * 32 + o];
        }
        BfF[gid] = (halfT)v;
    } else if (b < 8413){
        int e = (b - 8022) * 256 + tid;
        if (e < NE) atomicAdd(&deg[dstA[e]], 1.f);
    } else if (b < 8493){
        int t = (b - 8413) * 256 + tid;     // 20480
        if (t < 3072){ int k = t / 96, j = t % 96; WgT[t] = gWih[(size_t)j * 32 + k]; }
        else if (t < 6144){ int t2 = t - 3072; int k = t2 / 96, j = t2 % 96; WhT[t2] = gWhh[(size_t)j * 32 + k]; }
        else if (t < 14336){ int t2 = t - 6144; int k = t2 >> 7, j = t2 & 127; lWihT[t2] = lWih[(size_t)j * 64 + k]; }
        else if (t < 18432){ int t2 = t - 14336; int k = t2 >> 7, j = t2 & 127; lWhhT[t2] = lWhh[(size_t)j * 32 + k]; }
        else { int t2 = t - 18432; int k = t2 >> 5, c = t2 & 31; lin1T[t2] = lin1_W[(size_t)c * 64 + k]; }
    } else {
        int g = (b - 8493) * 256 + tid;
        if (g > NB) return;
        int lo = 0, hi = NN;
        while (lo < hi){
            int mid = (lo + hi) >> 1;
            if (batch[mid] < g) lo = mid + 1; else hi = mid;
        }
        starts[g] = lo;
    }
}

// =====================================================================
// k_msg4: NNConv message GEMM with double-buffered LDS staging of the
// shared B-stream (all 4 waves of a block consume the same B).
// Per 16KB K-group: compute from sB[g&1] -> ds_write sB[g^1] from
// prefetch regs -> issue loads for g+2 -> ONE barrier. Fully unrolled
// so all fragment indices are compile-time (no scratch).
// MFMA conventions identical to round-3-verified kernel.
// =====================================================================
__global__ __launch_bounds__(256, 2) void k_msg4(
    const halfT* __restrict__ ehF, const halfT* __restrict__ BfF,
    const halfT* __restrict__ hH,
    const int* __restrict__ src, const int* __restrict__ dst,
    float* __restrict__ aggr)
{
    __shared__ halfT sB[2][8192];        // 2 x 16KB
    int tid = threadIdx.x;
    int l = tid & 63;
    int wid = blockIdx.x * 4 + (tid >> 6);
    int m = l & 15, q = l >> 4;
    int eb = wid * 32;
    // stage group 0 -> LDS (via regs)
    half8 pre[4];
    #pragma unroll
    for (int p = 0; p < 4; p++)
        pre[p] = *(const half8*)(BfF + (size_t)(p * 256 + tid) * 8);
    #pragma unroll
    for (int p = 0; p < 4; p++)
        *(half8*)(&sB[0][(p * 256 + tid) * 8]) = pre[p];
    // per-wave operand fragments (latency overlaps staging)
    half8 u0[4], u1[4], ub0, ub1;
    {
        int e0 = eb + m;      int se0 = (e0 < NE) ? src[e0] : 0;
        int e1 = eb + 16 + m; int se1 = (e1 < NE) ? src[e1] : 0;
        const halfT* p0 = hH + (size_t)se0 * 32;
        const halfT* p1 = hH + (size_t)se1 * 32;
        #pragma unroll
        for (int j = 0; j < 4; j++){
            u0[j] = *(const half8*)(p0 + j * 8);
            u1[j] = *(const half8*)(p1 + j * 8);
        }
        ub0 = *(const half8*)(p0 + q * 8);
        ub1 = *(const half8*)(p1 + q * 8);
    }
    half8 eh0[4], eh1[4];
    {
        int g0 = eb >> 4;
        #pragma unroll
        for (int s = 0; s < 4; s++){
            eh0[s] = *(const half8*)(ehF + ((size_t)(g0 * 4 + s) * 64 + l) * 8);
            eh1[s] = *(const half8*)(ehF + ((size_t)((g0 + 1) * 4 + s) * 64 + l) * 8);
        }
    }
    __syncthreads();
    // prefetch group 1 into regs
    #pragma unroll
    for (int p = 0; p < 4; p++)
        pre[p] = *(const half8*)(BfF + (size_t)8192 + (size_t)(p * 256 + tid) * 8);
    f32x4 acc00 = {0,0,0,0}, acc01 = {0,0,0,0}, acc10 = {0,0,0,0}, acc11 = {0,0,0,0};
    #pragma unroll
    for (int g = 0; g < 16; g++){
        const int cur = g & 1;
        #pragma unroll
        for (int j = 0; j < 8; j++){
            const int ks = g * 8 + j;
            half8 b0 = *(const half8*)(&sB[cur][(j * 2 + 0) * 512 + l * 8]);
            half8 b1 = *(const half8*)(&sB[cur][(j * 2 + 1) * 512 + l * 8]);
            const int c = ks >> 2, s = ks & 3;
            halfT uc0 = u0[c >> 3][c & 7];
            halfT uc1 = u1[c >> 3][c & 7];
            half8 a0 = eh0[s] * uc0;
            half8 a1 = eh1[s] * uc1;
            acc00 = __builtin_amdgcn_mfma_f32_16x16x32_f16(a0, b0, acc00, 0, 0, 0);
            acc01 = __builtin_amdgcn_mfma_f32_16x16x32_f16(a0, b1, acc01, 0, 0, 0);
            acc10 = __builtin_amdgcn_mfma_f32_16x16x32_f16(a1, b0, acc10, 0, 0, 0);
            acc11 = __builtin_amdgcn_mfma_f32_16x16x32_f16(a1, b1, acc11, 0, 0, 0);
        }
        if (g + 1 < 16){
            #pragma unroll
            for (int p = 0; p < 4; p++)
                *(half8*)(&sB[cur ^ 1][(p * 256 + tid) * 8]) = pre[p];
            if (g + 2 < 16){
                #pragma unroll
                for (int p = 0; p < 4; p++)
                    pre[p] = *(const half8*)(BfF + (size_t)(g + 2) * 8192 + (size_t)(p * 256 + tid) * 8);
            }
        }
        __syncthreads();
    }
    {   // bias K-tile (ks = 128) straight from global (L2-hot, one shot)
        half8 b0 = *(const half8*)(BfF + (size_t)256 * 512 + l * 8);
        half8 b1 = *(const half8*)(BfF + (size_t)257 * 512 + l * 8);
        acc00 = __builtin_amdgcn_mfma_f32_16x16x32_f16(ub0, b0, acc00, 0, 0, 0);
        acc01 = __builtin_amdgcn_mfma_f32_16x16x32_f16(ub0, b1, acc01, 0, 0, 0);
        acc10 = __builtin_amdgcn_mfma_f32_16x16x32_f16(ub1, b0, acc10, 0, 0, 0);
        acc11 = __builtin_amdgcn_mfma_f32_16x16x32_f16(ub1, b1, acc11, 0, 0, 0);
    }
    // scatter: lane holds msg[e = eb+G*16+q*4+r][o = nt*16+m]
    #pragma unroll
    for (int r = 0; r < 4; r++){
        int ea0 = eb + q * 4 + r;
        if (ea0 < NE){
            int d = dst[ea0];
            atomicAdd(&aggr[(size_t)d * 32 + m],      acc00[r]);
            atomicAdd(&aggr[(size_t)d * 32 + 16 + m], acc01[r]);
        }
        int ea1 = eb + 16 + q * 4 + r;
        if (ea1 < NE){
            int d = dst[ea1];
            atomicAdd(&aggr[(size_t)d * 32 + m],      acc10[r]);
            atomicAdd(&aggr[(size_t)d * 32 + 16 + m], acc11[r]);
        }
    }
}

// =====================================================================
// k_gru: wave-parallel (lane = output channel, 32 lanes per node).  [unchanged]
// =====================================================================
__global__ __launch_bounds__(256) void k_gru(
    float* __restrict__ aggr, const float* __restrict__ deg, float* __restrict__ h,
    halfT* __restrict__ hH,
    const float* __restrict__ rootW, const float* __restrict__ cb,
    const float* __restrict__ WgT, const float* __restrict__ WhT,
    const float* __restrict__ gbih, const float* __restrict__ gbhh)
{
    int tid = threadIdx.x;
    int i = blockIdx.x * 8 + (tid >> 5);
    int c = tid & 31;
    size_t base = (size_t)i * 32 + c;
    float hq = h[base];
    float av = aggr[base];
    aggr[base] = 0.f;
    float invd = 1.f / fmaxf(deg[i], 1.f);
    float mv = av * invd + cb[c];
    #pragma unroll 8
    for (int k = 0; k < 32; k++)
        mv += __shfl(hq, k, 32) * rootW[k * 32 + c];
    mv = fmaxf(mv, 0.f);
    float gr = gbih[c],      hr = gbhh[c];
    float gz = gbih[32 + c], hz = gbhh[32 + c];
    float gn = gbih[64 + c], hn = gbhh[64 + c];
    #pragma unroll 4
    for (int k = 0; k < 32; k++){
        float mk = __shfl(mv, k, 32);
        float hk = __shfl(hq, k, 32);
        const float* wg = WgT + k * 96;
        const float* wh = WhT + k * 96;
        gr += mk * wg[c];      hr += hk * wh[c];
        gz += mk * wg[32 + c]; hz += hk * wh[32 + c];
        gn += mk * wg[64 + c]; hn += hk * wh[64 + c];
    }
    float r = sigf(gr + hr);
    float z = sigf(gz + hz);
    float n = tanhf(gn + r * hn);
    float hnew = (1.f - z) * n + z * hq;
    h[base] = hnew;
    hH[base] = (halfT)hnew;
}

// =====================================================================
// k_s2s: entire Set2Set (3x LSTM + attention) + final MLP.  [unchanged]
// =====================================================================
__global__ __launch_bounds__(64) void k_s2s(
    const float* __restrict__ h, const int* __restrict__ starts,
    const float* __restrict__ lWihT, const float* __restrict__ lWhhT,
    const float* __restrict__ lbih, const float* __restrict__ lbhh,
    const float* __restrict__ lin1T, const float* __restrict__ lin1_b,
    const float* __restrict__ lin2W, const float* __restrict__ lin2b,
    float* __restrict__ out)
{
    __shared__ float ebuf[256];
    int g = blockIdx.x, l = threadIdx.x;
    int s0 = starts[g], s1 = starts[g + 1];
    int c = l & 31, grp = l >> 5;
    float qs = 0.f, hsv = 0.f, csv = 0.f;
    for (int t = 0; t < 3; t++){
        float a1 = lbih[l] + lbhh[l];
        float a2 = lbih[l + 64] + lbhh[l + 64];
        #pragma unroll 8
        for (int k = 0; k < 64; k++){
            float qk = __shfl(qs, k);
            a1 += qk * lWihT[k * 128 + l];
            a2 += qk * lWihT[k * 128 + 64 + l];
        }
        #pragma unroll 8
        for (int k = 0; k < 32; k++){
            float hk = __shfl(qs, k);
            a1 += hk * lWhhT[k * 128 + l];
            a2 += hk * lWhhT[k * 128 + 64 + l];
        }
        float gate1 = sigf(a1);
        float gate2 = (l < 32) ? tanhf(a2) : sigf(a2);
        float fv = __shfl(gate1, c + 32);
        float ov = __shfl(gate2, c + 32);
        if (l < 32){
            csv = fv * csv + gate1 * gate2;
            hsv = ov * tanhf(csv);
        }
        float hq = __shfl(hsv, c);
        float mx = -3.4e38f;
        for (int idx = s0 + grp; idx < s1; idx += 2){
            float p = h[(size_t)idx * 32 + c] * hq;
            p += __shfl_xor(p, 1);  p += __shfl_xor(p, 2);
            p += __shfl_xor(p, 4);  p += __shfl_xor(p, 8);
            p += __shfl_xor(p, 16);
            int ii = idx - s0;
            if (c == 0 && ii < 256) ebuf[ii] = p;
            mx = fmaxf(mx, p);
        }
        mx = fmaxf(mx, __shfl_xor(mx, 32));
        __syncthreads();
        int n = s1 - s0;
        int nc = n < 256 ? n : 256;
        float ss = 0.f;
        for (int ii = l; ii < nc; ii += 64) ss += expf(ebuf[ii] - mx);
        for (int idx = s0 + 256 + grp; idx < s1; idx += 2){
            float p = h[(size_t)idx * 32 + c] * hq;
            p += __shfl_xor(p, 1);  p += __shfl_xor(p, 2);
            p += __shfl_xor(p, 4);  p += __shfl_xor(p, 8);
            p += __shfl_xor(p, 16);
            if (c == 0) ss += expf(p - mx);
        }
        ss += __shfl_xor(ss, 1);  ss += __shfl_xor(ss, 2);
        ss += __shfl_xor(ss, 4);  ss += __shfl_xor(ss, 8);
        ss += __shfl_xor(ss, 16); ss += __shfl_xor(ss, 32);
        float inv = (ss > 0.f) ? 1.f / ss : 0.f;
        float acc = 0.f;
        for (int idx = s0 + grp; idx < s1; idx += 2){
            int ii = idx - s0;
            float p;
            if (ii < 256) p = ebuf[ii];
            else {
                p = h[(size_t)idx * 32 + c] * hq;
                p += __shfl_xor(p, 1);  p += __shfl_xor(p, 2);
                p += __shfl_xor(p, 4);  p += __shfl_xor(p, 8);
                p += __shfl_xor(p, 16);
            }
            float a = expf(p - mx) * inv;
            acc += a * h[(size_t)idx * 32 + c];
        }
        acc += __shfl_xor(acc, 32);
        qs = (l < 32) ? hsv : acc;
        __syncthreads();
    }
    float s = lin1_b[c];
    #pragma unroll 8
    for (int k = 0; k < 64; k++){
        float qk = __shfl(qs, k);
        s += qk * lin1T[k * 32 + c];
    }
    float pp = (l < 32) ? fmaxf(s, 0.f) * lin2W[c] : 0.f;
    pp += __shfl_xor(pp, 1);  pp += __shfl_xor(pp, 2);
    pp += __shfl_xor(pp, 4);  pp += __shfl_xor(pp, 8);
    pp += __shfl_xor(pp, 16); pp += __shfl_xor(pp, 32);
    if (l == 0) out[g] = pp + lin2b[0];
}

extern "C" void kernel_launch(void* const* d_in, const int* in_sizes, int n_in,
                              void* d_out, int out_size, void* d_ws, size_t ws_size,
                              hipStream_t stream){
    (void)in_sizes; (void)n_in; (void)out_size;
    const float* x        = (const float*)d_in[0];
    const float* ea       = (const float*)d_in[1];
    const int*   ei       = (const int*)d_in[2];
    const int*   batch    = (const int*)d_in[3];
    const float* lin0_W   = (const float*)d_in[4];
    const float* lin0_b   = (const float*)d_in[5];
    const float* mlp_W1   = (const float*)d_in[6];
    const float* mlp_b1   = (const float*)d_in[7];
    const float* mlp_W2   = (const float*)d_in[8];
    const float* mlp_b2   = (const float*)d_in[9];
    const float* root_W   = (const float*)d_in[10];
    const float* conv_b   = (const float*)d_in[11];
    const float* gWih     = (const float*)d_in[12];
    const float* gWhh     = (const float*)d_in[13];
    const float* gbih     = (const float*)d_in[14];
    const float* gbhh     = (const float*)d_in[15];
    const float* lWih     = (const float*)d_in[16];
    const float* lWhh     = (const float*)d_in[17];
    const float* lbih     = (const float*)d_in[18];
    const float* lbhh     = (const float*)d_in[19];
    const float* lin1_W   = (const float*)d_in[20];
    const float* lin1_b   = (const float*)d_in[21];
    const float* lin2_W   = (const float*)d_in[22];
    const float* lin2_b   = (const float*)d_in[23];
    const int* src = ei;
    const int* dst = ei + NE;
    float* out = (float*)d_out;

    char* w = (char*)d_ws;
    size_t off = 0;
    auto alloc = [&](size_t bytes) -> void* {
        void* p = w + off;
        off = (off + bytes + 255) & ~(size_t)255;
        return p;
    };
    float* deg    = (float*)alloc((size_t)NN * 4);            // contiguous with aggr
    float* aggr   = (float*)alloc((size_t)NN * 32 * 4);
    float* h      = (float*)alloc((size_t)NN * 32 * 4);
    halfT* hH     = (halfT*)alloc((size_t)NN * 32 * 2);
    halfT* ehF    = (halfT*)alloc((size_t)NEP * 128 * 2);
    halfT* BfF    = (halfT*)alloc((size_t)129 * 2 * 64 * 8 * 2);
    int*   starts = (int*)alloc((size_t)(NB + 1) * 4);
    float* WgT    = (float*)alloc((size_t)3072 * 4);
    float* WhT    = (float*)alloc((size_t)3072 * 4);
    float* lWihT  = (float*)alloc((size_t)8192 * 4);
    float* lWhhT  = (float*)alloc((size_t)4096 * 4);
    float* lin1T  = (float*)alloc((size_t)2048 * 4);
    if (ws_size < off) return;   // cannot run

    hipMemsetAsync(deg, 0, (size_t)NN * 4 + (size_t)NN * 32 * 4, stream);

    k_setup<<<8498, 256, 0, stream>>>(x, lin0_W, lin0_b, ea, mlp_W1, mlp_b1,
        mlp_W2, mlp_b2, dst, batch, gWih, gWhh, lWih, lWhh, lin1_W,
        h, hH, ehF, BfF, deg, WgT, WhT, lWihT, lWhhT, lin1T, starts);

    for (int t = 0; t < 3; t++){
        k_msg4<<<NEP / 128, 256, 0, stream>>>(ehF, BfF, hH, src, dst, aggr);
        k_gru<<<NN / 8, 256, 0, stream>>>(aggr, deg, h, hH, root_W, conv_b,
                                          WgT, WhT, gbih, gbhh);
    }
    k_s2s<<<NB, 64, 0, stream>>>(h, starts, lWihT, lWhhT, lbih, lbhh,
                                 lin1T, lin1_b, lin2_W, lin2_b, out);
}

// Round 11
// 288.485 us; speedup vs baseline: 3.3845x; 1.0864x over previous
//
#include <hip/hip_runtime.h>
#include <hip/hip_bf16.h>
#include <cstdint>

#define NN 40000
#define NE 100000
#define NEP 100096           // 32-aligned edge count
#define NB 1024
#define MAXN 192             // per-graph LDS node cache capacity

typedef _Float16 halfT;
typedef _Float16 half8 __attribute__((ext_vector_type(8)));
typedef float f32x4 __attribute__((ext_vector_type(4)));

static __device__ __forceinline__ float sigf(float x){ return 1.f/(1.f + expf(-x)); }

// =====================================================================
// k_setup: one kernel, 6 block-ranges (all vectorized)  [unchanged from R10]
// =====================================================================
__global__ __launch_bounds__(256) void k_setup(
    const float* __restrict__ x, const float* __restrict__ lin0_W, const float* __restrict__ lin0_b,
    const float* __restrict__ ea, const float* __restrict__ W1, const float* __restrict__ b1,
    const float* __restrict__ W2, const float* __restrict__ b2,
    const int* __restrict__ dstA, const int* __restrict__ batch,
    const float* __restrict__ gWih, const float* __restrict__ gWhh,
    const float* __restrict__ lWih, const float* __restrict__ lWhh, const float* __restrict__ lin1_W,
    float* __restrict__ h, halfT* __restrict__ hH, halfT* __restrict__ ehF, halfT* __restrict__ BfF,
    float* __restrict__ deg, float* __restrict__ WgT, float* __restrict__ WhT,
    float* __restrict__ lWihT, float* __restrict__ lWhhT, float* __restrict__ lin1T,
    int* __restrict__ starts)
{
    int b = blockIdx.x, tid = threadIdx.x;
    if (b < 1250){
        __shared__ float sW[32 * 30];
        __shared__ float sB[32];
        for (int idx = tid; idx < 960; idx += 256) sW[idx] = lin0_W[idx];
        if (tid < 32) sB[tid] = lin0_b[tid];
        __syncthreads();
        int t8 = b * 256 + tid;             // [0, NN*8)
        int i = t8 >> 3, q4 = t8 & 7;       // node, channel-quad
        const float* xr = x + (size_t)i * 30;
        float xv[30];
        #pragma unroll
        for (int f = 0; f < 30; f++) xv[f] = xr[f];
        float r[4];
        #pragma unroll
        for (int cc = 0; cc < 4; cc++){
            int c = q4 * 4 + cc;
            const float* wr = &sW[c * 30];
            float s = sB[c];
            #pragma unroll
            for (int f = 0; f < 30; f++) s += xv[f] * wr[f];
            r[cc] = fmaxf(s, 0.f);
        }
        *(float4*)(h + (size_t)i * 32 + q4 * 4) = *(float4*)r;
        halfT rh[4];
        #pragma unroll
        for (int cc = 0; cc < 4; cc++) rh[cc] = (halfT)r[cc];
        *(uint2*)(hH + (size_t)i * 32 + q4 * 4) = *(uint2*)rh;
    } else if (b < 7506){
        __shared__ float sW1[128 * 11];
        __shared__ float sb1[128];
        for (int idx = tid; idx < 1408; idx += 256) sW1[idx] = W1[idx];
        if (tid < 128) sb1[tid] = b1[tid];
        __syncthreads();
        int t8 = (b - 1250) * 256 + tid;    // [0, NEP*16)
        int ch = t8 & 63;
        int s4 = (t8 >> 6) & 3;
        int g16 = t8 >> 8;
        int m = ch & 15, q = ch >> 4;       // lane-linear content
        int e = g16 * 16 + m;
        int kb = 32 * s4 + q * 8;
        halfT v[8];
        if (e < NE){
            const float* xr = ea + (size_t)e * 11;
            float xv[11];
            #pragma unroll
            for (int f = 0; f < 11; f++) xv[f] = xr[f];
            #pragma unroll
            for (int i8 = 0; i8 < 8; i8++){
                int k = kb + i8;
                const float* wr = &sW1[k * 11];
                float s = sb1[k];
                #pragma unroll
                for (int f = 0; f < 11; f++) s += xv[f] * wr[f];
                v[i8] = (halfT)fmaxf(s, 0.f);
            }
        } else {
            #pragma unroll
            for (int i8 = 0; i8 < 8; i8++) v[i8] = (halfT)0.f;
        }
        *(half8*)(ehF + (size_t)t8 * 8) = *(half8*)v;
    } else if (b < 8022){
        int gid = (b - 7506) * 256 + tid;   // 129*2*64*8 = 132096
        int i8 = gid & 7;
        int ch = (gid >> 3) & 63;
        int nt = (gid >> 9) & 1;
        int ks = gid >> 10;
        int m = ch & 15, q = ch >> 4;       // lane-linear content
        int o = nt * 16 + m;
        float v;
        if (ks < 128){
            int c = ks >> 2;
            int k = 32 * (ks & 3) + q * 8 + i8;
            v = W2[(size_t)(c * 32 + o) * 128 + k];
        } else {
            int c = q * 8 + i8;
            v = b2[c * 32 + o];
        }
        BfF[gid] = (halfT)v;
    } else if (b < 8413){
        int e = (b - 8022) * 256 + tid;
        if (e < NE) atomicAdd(&deg[dstA[e]], 1.f);
    } else if (b < 8493){
        int t = (b - 8413) * 256 + tid;     // 20480
        if (t < 3072){ int k = t / 96, j = t % 96; WgT[t] = gWih[(size_t)j * 32 + k]; }
        else if (t < 6144){ int t2 = t - 3072; int k = t2 / 96, j = t2 % 96; WhT[t2] = gWhh[(size_t)j * 32 + k]; }
        else if (t < 14336){ int t2 = t - 6144; int k = t2 >> 7, j = t2 & 127; lWihT[t2] = lWih[(size_t)j * 64 + k]; }
        else if (t < 18432){ int t2 = t - 14336; int k = t2 >> 7, j = t2 & 127; lWhhT[t2] = lWhh[(size_t)j * 32 + k]; }
        else { int t2 = t - 18432; int k = t2 >> 5, c = t2 & 31; lin1T[t2] = lin1_W[(size_t)c * 64 + k]; }
    } else {
        int g = (b - 8493) * 256 + tid;
        if (g > NB) return;
        int lo = 0, hi = NN;
        while (lo < hi){
            int mid = (lo + hi) >> 1;
            if (batch[mid] < g) lo = mid + 1; else hi = mid;
        }
        starts[g] = lo;
    }
}

// =====================================================================
// k_msg4: NNConv message GEMM, double-buffered LDS B-stream.  [unchanged]
// =====================================================================
__global__ __launch_bounds__(256, 2) void k_msg4(
    const halfT* __restrict__ ehF, const halfT* __restrict__ BfF,
    const halfT* __restrict__ hH,
    const int* __restrict__ src, const int* __restrict__ dst,
    float* __restrict__ aggr)
{
    __shared__ halfT sB[2][8192];        // 2 x 16KB
    int tid = threadIdx.x;
    int l = tid & 63;
    int wid = blockIdx.x * 4 + (tid >> 6);
    int m = l & 15, q = l >> 4;
    int eb = wid * 32;
    half8 pre[4];
    #pragma unroll
    for (int p = 0; p < 4; p++)
        pre[p] = *(const half8*)(BfF + (size_t)(p * 256 + tid) * 8);
    #pragma unroll
    for (int p = 0; p < 4; p++)
        *(half8*)(&sB[0][(p * 256 + tid) * 8]) = pre[p];
    half8 u0[4], u1[4], ub0, ub1;
    {
        int e0 = eb + m;      int se0 = (e0 < NE) ? src[e0] : 0;
        int e1 = eb + 16 + m; int se1 = (e1 < NE) ? src[e1] : 0;
        const halfT* p0 = hH + (size_t)se0 * 32;
        const halfT* p1 = hH + (size_t)se1 * 32;
        #pragma unroll
        for (int j = 0; j < 4; j++){
            u0[j] = *(const half8*)(p0 + j * 8);
            u1[j] = *(const half8*)(p1 + j * 8);
        }
        ub0 = *(const half8*)(p0 + q * 8);
        ub1 = *(const half8*)(p1 + q * 8);
    }
    half8 eh0[4], eh1[4];
    {
        int g0 = eb >> 4;
        #pragma unroll
        for (int s = 0; s < 4; s++){
            eh0[s] = *(const half8*)(ehF + ((size_t)(g0 * 4 + s) * 64 + l) * 8);
            eh1[s] = *(const half8*)(ehF + ((size_t)((g0 + 1) * 4 + s) * 64 + l) * 8);
        }
    }
    __syncthreads();
    #pragma unroll
    for (int p = 0; p < 4; p++)
        pre[p] = *(const half8*)(BfF + (size_t)8192 + (size_t)(p * 256 + tid) * 8);
    f32x4 acc00 = {0,0,0,0}, acc01 = {0,0,0,0}, acc10 = {0,0,0,0}, acc11 = {0,0,0,0};
    #pragma unroll
    for (int g = 0; g < 16; g++){
        const int cur = g & 1;
        #pragma unroll
        for (int j = 0; j < 8; j++){
            const int ks = g * 8 + j;
            half8 b0 = *(const half8*)(&sB[cur][(j * 2 + 0) * 512 + l * 8]);
            half8 b1 = *(const half8*)(&sB[cur][(j * 2 + 1) * 512 + l * 8]);
            const int c = ks >> 2, s = ks & 3;
            halfT uc0 = u0[c >> 3][c & 7];
            halfT uc1 = u1[c >> 3][c & 7];
            half8 a0 = eh0[s] * uc0;
            half8 a1 = eh1[s] * uc1;
            acc00 = __builtin_amdgcn_mfma_f32_16x16x32_f16(a0, b0, acc00, 0, 0, 0);
            acc01 = __builtin_amdgcn_mfma_f32_16x16x32_f16(a0, b1, acc01, 0, 0, 0);
            acc10 = __builtin_amdgcn_mfma_f32_16x16x32_f16(a1, b0, acc10, 0, 0, 0);
            acc11 = __builtin_amdgcn_mfma_f32_16x16x32_f16(a1, b1, acc11, 0, 0, 0);
        }
        if (g + 1 < 16){
            #pragma unroll
            for (int p = 0; p < 4; p++)
                *(half8*)(&sB[cur ^ 1][(p * 256 + tid) * 8]) = pre[p];
            if (g + 2 < 16){
                #pragma unroll
                for (int p = 0; p < 4; p++)
                    pre[p] = *(const half8*)(BfF + (size_t)(g + 2) * 8192 + (size_t)(p * 256 + tid) * 8);
            }
        }
        __syncthreads();
    }
    {
        half8 b0 = *(const half8*)(BfF + (size_t)256 * 512 + l * 8);
        half8 b1 = *(const half8*)(BfF + (size_t)257 * 512 + l * 8);
        acc00 = __builtin_amdgcn_mfma_f32_16x16x32_f16(ub0, b0, acc00, 0, 0, 0);
        acc01 = __builtin_amdgcn_mfma_f32_16x16x32_f16(ub0, b1, acc01, 0, 0, 0);
        acc10 = __builtin_amdgcn_mfma_f32_16x16x32_f16(ub1, b0, acc10, 0, 0, 0);
        acc11 = __builtin_amdgcn_mfma_f32_16x16x32_f16(ub1, b1, acc11, 0, 0, 0);
    }
    #pragma unroll
    for (int r = 0; r < 4; r++){
        int ea0 = eb + q * 4 + r;
        if (ea0 < NE){
            int d = dst[ea0];
            atomicAdd(&aggr[(size_t)d * 32 + m],      acc00[r]);
            atomicAdd(&aggr[(size_t)d * 32 + 16 + m], acc01[r]);
        }
        int ea1 = eb + 16 + q * 4 + r;
        if (ea1 < NE){
            int d = dst[ea1];
            atomicAdd(&aggr[(size_t)d * 32 + m],      acc10[r]);
            atomicAdd(&aggr[(size_t)d * 32 + 16 + m], acc11[r]);
        }
    }
}

// =====================================================================
// k_gru: wave-parallel (lane = output channel, 32 lanes per node).  [unchanged]
// =====================================================================
__global__ __launch_bounds__(256) void k_gru(
    float* __restrict__ aggr, const float* __restrict__ deg, float* __restrict__ h,
    halfT* __restrict__ hH,
    const float* __restrict__ rootW, const float* __restrict__ cb,
    const float* __restrict__ WgT, const float* __restrict__ WhT,
    const float* __restrict__ gbih, const float* __restrict__ gbhh)
{
    int tid = threadIdx.x;
    int i = blockIdx.x * 8 + (tid >> 5);
    int c = tid & 31;
    size_t base = (size_t)i * 32 + c;
    float hq = h[base];
    float av = aggr[base];
    aggr[base] = 0.f;
    float invd = 1.f / fmaxf(deg[i], 1.f);
    float mv = av * invd + cb[c];
    #pragma unroll 8
    for (int k = 0; k < 32; k++)
        mv += __shfl(hq, k, 32) * rootW[k * 32 + c];
    mv = fmaxf(mv, 0.f);
    float gr = gbih[c],      hr = gbhh[c];
    float gz = gbih[32 + c], hz = gbhh[32 + c];
    float gn = gbih[64 + c], hn = gbhh[64 + c];
    #pragma unroll 4
    for (int k = 0; k < 32; k++){
        float mk = __shfl(mv, k, 32);
        float hk = __shfl(hq, k, 32);
        const float* wg = WgT + k * 96;
        const float* wh = WhT + k * 96;
        gr += mk * wg[c];      hr += hk * wh[c];
        gz += mk * wg[32 + c]; hz += hk * wh[32 + c];
        gn += mk * wg[64 + c]; hn += hk * wh[64 + c];
    }
    float r = sigf(gr + hr);
    float z = sigf(gz + hz);
    float n = tanhf(gn + r * hn);
    float hnew = (1.f - z) * n + z * hq;
    h[base] = hnew;
    hH[base] = (halfT)hnew;
}

// =====================================================================
// k_s2s R11: graph's h-rows cached in LDS once (h is invariant during
// Set2Set). Pass A: lane-per-node dot (32 LDS FMAs, stride-33 rows =
// 2-way banks = free). Pass B: exp/sum in place. Pass C: lane-per-channel
// weighted sum. Graphs >MAXN nodes fall back to global per node.
// =====================================================================
__global__ __launch_bounds__(64) void k_s2s(
    const float* __restrict__ h, const int* __restrict__ starts,
    const float* __restrict__ lWihT, const float* __restrict__ lWhhT,
    const float* __restrict__ lbih, const float* __restrict__ lbhh,
    const float* __restrict__ lin1T, const float* __restrict__ lin1_b,
    const float* __restrict__ lin2W, const float* __restrict__ lin2b,
    float* __restrict__ e_buf, float* __restrict__ out)
{
    __shared__ float hl[MAXN * 33];
    __shared__ float al[MAXN];
    __shared__ float hsl[32];
    int g = blockIdx.x, l = threadIdx.x;
    int s0 = starts[g], s1 = starts[g + 1];
    int n = s1 - s0;
    int c = l & 31, grp = l >> 5;
    // stage h rows into LDS (coalesced global, padded LDS rows)
    int nl = (n < MAXN) ? n : MAXN;
    for (int idx = l; idx < nl * 32; idx += 64)
        hl[(idx >> 5) * 33 + (idx & 31)] = h[(size_t)s0 * 32 + idx];
    __syncthreads();
    float qs = 0.f, hsv = 0.f, csv = 0.f;
    for (int t = 0; t < 3; t++){
        // LSTM gates: lane computes j1=l, j2=l+64 (torch order i,f,g,o)
        float a1 = lbih[l] + lbhh[l];
        float a2 = lbih[l + 64] + lbhh[l + 64];
        #pragma unroll 8
        for (int k = 0; k < 64; k++){
            float qk = __shfl(qs, k);
            a1 += qk * lWihT[k * 128 + l];
            a2 += qk * lWihT[k * 128 + 64 + l];
        }
        #pragma unroll 8
        for (int k = 0; k < 32; k++){
            float hk = __shfl(qs, k);
            a1 += hk * lWhhT[k * 128 + l];
            a2 += hk * lWhhT[k * 128 + 64 + l];
        }
        float gate1 = sigf(a1);
        float gate2 = (l < 32) ? tanhf(a2) : sigf(a2);
        float fv = __shfl(gate1, c + 32);
        float ov = __shfl(gate2, c + 32);
        if (l < 32){
            csv = fv * csv + gate1 * gate2;
            hsv = ov * tanhf(csv);
            hsl[l] = hsv;
        }
        __syncthreads();
        // pass A: lane-per-node dot + local max
        float lmax = -3.4e38f;
        for (int i = l; i < n; i += 64){
            const float* hr = (i < MAXN) ? &hl[i * 33] : &h[(size_t)(s0 + i) * 32];
            float p = 0.f;
            #pragma unroll
            for (int c2 = 0; c2 < 32; c2++) p += hr[c2] * hsl[c2];
            if (i < MAXN) al[i] = p; else e_buf[s0 + i] = p;
            lmax = fmaxf(lmax, p);
        }
        #pragma unroll
        for (int o = 1; o < 64; o <<= 1) lmax = fmaxf(lmax, __shfl_xor(lmax, o));
        // pass B: exp + sum (in place)
        float lsum = 0.f;
        for (int i = l; i < n; i += 64){
            float e = (i < MAXN) ? al[i] : e_buf[s0 + i];
            float a = expf(e - lmax);
            if (i < MAXN) al[i] = a; else e_buf[s0 + i] = a;
            lsum += a;
        }
        #pragma unroll
        for (int o = 1; o < 64; o <<= 1) lsum += __shfl_xor(lsum, o);
        float inv = (lsum > 0.f) ? 1.f / lsum : 0.f;
        __syncthreads();
        // pass C: lane-per-channel weighted sum (half-wave splits nodes)
        float acc = 0.f;
        for (int i = grp; i < n; i += 2){
            float a = (i < MAXN) ? al[i] : e_buf[s0 + i];
            const float* hr = (i < MAXN) ? &hl[i * 33] : &h[(size_t)(s0 + i) * 32];
            acc += a * hr[c];
        }
        acc *= inv;
        acc += __shfl_xor(acc, 32);
        qs = (l < 32) ? hsv : acc;
        __syncthreads();
    }
    // final: out = relu(q_star@lin1^T+b1) @ lin2^T + b2
    float s = lin1_b[c];
    #pragma unroll 8
    for (int k = 0; k < 64; k++){
        float qk = __shfl(qs, k);
        s += qk * lin1T[k * 32 + c];
    }
    float pp = (l < 32) ? fmaxf(s, 0.f) * lin2W[c] : 0.f;
    pp += __shfl_xor(pp, 1);  pp += __shfl_xor(pp, 2);
    pp += __shfl_xor(pp, 4);  pp += __shfl_xor(pp, 8);
    pp += __shfl_xor(pp, 16); pp += __shfl_xor(pp, 32);
    if (l == 0) out[g] = pp + lin2b[0];
}

extern "C" void kernel_launch(void* const* d_in, const int* in_sizes, int n_in,
                              void* d_out, int out_size, void* d_ws, size_t ws_size,
                              hipStream_t stream){
    (void)in_sizes; (void)n_in; (void)out_size;
    const float* x        = (const float*)d_in[0];
    const float* ea       = (const float*)d_in[1];
    const int*   ei       = (const int*)d_in[2];
    const int*   batch    = (const int*)d_in[3];
    const float* lin0_W   = (const float*)d_in[4];
    const float* lin0_b   = (const float*)d_in[5];
    const float* mlp_W1   = (const float*)d_in[6];
    const float* mlp_b1   = (const float*)d_in[7];
    const float* mlp_W2   = (const float*)d_in[8];
    const float* mlp_b2   = (const float*)d_in[9];
    const float* root_W   = (const float*)d_in[10];
    const float* conv_b   = (const float*)d_in[11];
    const float* gWih     = (const float*)d_in[12];
    const float* gWhh     = (const float*)d_in[13];
    const float* gbih     = (const float*)d_in[14];
    const float* gbhh     = (const float*)d_in[15];
    const float* lWih     = (const float*)d_in[16];
    const float* lWhh     = (const float*)d_in[17];
    const float* lbih     = (const float*)d_in[18];
    const float* lbhh     = (const float*)d_in[19];
    const float* lin1_W   = (const float*)d_in[20];
    const float* lin1_b   = (const float*)d_in[21];
    const float* lin2_W   = (const float*)d_in[22];
    const float* lin2_b   = (const float*)d_in[23];
    const int* src = ei;
    const int* dst = ei + NE;
    float* out = (float*)d_out;

    char* w = (char*)d_ws;
    size_t off = 0;
    auto alloc = [&](size_t bytes) -> void* {
        void* p = w + off;
        off = (off + bytes + 255) & ~(size_t)255;
        return p;
    };
    float* deg    = (float*)alloc((size_t)NN * 4);            // contiguous with aggr
    float* aggr   = (float*)alloc((size_t)NN * 32 * 4);
    float* h      = (float*)alloc((size_t)NN * 32 * 4);
    halfT* hH     = (halfT*)alloc((size_t)NN * 32 * 2);
    halfT* ehF    = (halfT*)alloc((size_t)NEP * 128 * 2);
    halfT* BfF    = (halfT*)alloc((size_t)129 * 2 * 64 * 8 * 2);
    int*   starts = (int*)alloc((size_t)(NB + 1) * 4);
    float* WgT    = (float*)alloc((size_t)3072 * 4);
    float* WhT    = (float*)alloc((size_t)3072 * 4);
    float* lWihT  = (float*)alloc((size_t)8192 * 4);
    float* lWhhT  = (float*)alloc((size_t)4096 * 4);
    float* lin1T  = (float*)alloc((size_t)2048 * 4);
    float* e_buf  = (float*)alloc((size_t)NN * 4);
    if (ws_size < off) return;   // cannot run

    hipMemsetAsync(deg, 0, (size_t)NN * 4 + (size_t)NN * 32 * 4, stream);

    k_setup<<<8498, 256, 0, stream>>>(x, lin0_W, lin0_b, ea, mlp_W1, mlp_b1,
        mlp_W2, mlp_b2, dst, batch, gWih, gWhh, lWih, lWhh, lin1_W,
        h, hH, ehF, BfF, deg, WgT, WhT, lWihT, lWhhT, lin1T, starts);

    for (int t = 0; t < 3; t++){
        k_msg4<<<NEP / 128, 256, 0, stream>>>(ehF, BfF, hH, src, dst, aggr);
        k_gru<<<NN / 8, 256, 0, stream>>>(aggr, deg, h, hH, root_W, conv_b,
                                          WgT, WhT, gbih, gbhh);
    }
    k_s2s<<<NB, 64, 0, stream>>>(h, starts, lWihT, lWhhT, lbih, lbhh,
                                 lin1T, lin1_b, lin2_W, lin2_b, e_buf, out);
}

// Round 12
// 265.946 us; speedup vs baseline: 3.6713x; 1.0847x over previous
//
#include <hip/hip_runtime.h>
#include <hip/hip_bf16.h>
#include <cstdint>

#define NN 40000
#define NE 100000
#define NEP 100096           // 32-aligned edge count
#define NB 1024
#define MAXN 192             // per-graph LDS node cache capacity

typedef _Float16 halfT;
typedef _Float16 half8 __attribute__((ext_vector_type(8)));
typedef float f32x4 __attribute__((ext_vector_type(4)));

static __device__ __forceinline__ float sigf(float x){ return 1.f/(1.f + expf(-x)); }

// =====================================================================
// k_setup: one kernel, 6 block-ranges (all vectorized)  [unchanged from R11]
// =====================================================================
__global__ __launch_bounds__(256) void k_setup(
    const float* __restrict__ x, const float* __restrict__ lin0_W, const float* __restrict__ lin0_b,
    const float* __restrict__ ea, const float* __restrict__ W1, const float* __restrict__ b1,
    const float* __restrict__ W2, const float* __restrict__ b2,
    const int* __restrict__ dstA, const int* __restrict__ batch,
    const float* __restrict__ gWih, const float* __restrict__ gWhh,
    const float* __restrict__ lWih, const float* __restrict__ lWhh, const float* __restrict__ lin1_W,
    float* __restrict__ h, halfT* __restrict__ hH, halfT* __restrict__ ehF, halfT* __restrict__ BfF,
    float* __restrict__ deg, float* __restrict__ WgT, float* __restrict__ WhT,
    float* __restrict__ lWihT, float* __restrict__ lWhhT, float* __restrict__ lin1T,
    int* __restrict__ starts)
{
    int b = blockIdx.x, tid = threadIdx.x;
    if (b < 1250){
        __shared__ float sW[32 * 30];
        __shared__ float sB[32];
        for (int idx = tid; idx < 960; idx += 256) sW[idx] = lin0_W[idx];
        if (tid < 32) sB[tid] = lin0_b[tid];
        __syncthreads();
        int t8 = b * 256 + tid;             // [0, NN*8)
        int i = t8 >> 3, q4 = t8 & 7;       // node, channel-quad
        const float* xr = x + (size_t)i * 30;
        float xv[30];
        #pragma unroll
        for (int f = 0; f < 30; f++) xv[f] = xr[f];
        float r[4];
        #pragma unroll
        for (int cc = 0; cc < 4; cc++){
            int c = q4 * 4 + cc;
            const float* wr = &sW[c * 30];
            float s = sB[c];
            #pragma unroll
            for (int f = 0; f < 30; f++) s += xv[f] * wr[f];
            r[cc] = fmaxf(s, 0.f);
        }
        *(float4*)(h + (size_t)i * 32 + q4 * 4) = *(float4*)r;
        halfT rh[4];
        #pragma unroll
        for (int cc = 0; cc < 4; cc++) rh[cc] = (halfT)r[cc];
        *(uint2*)(hH + (size_t)i * 32 + q4 * 4) = *(uint2*)rh;
    } else if (b < 7506){
        __shared__ float sW1[128 * 11];
        __shared__ float sb1[128];
        for (int idx = tid; idx < 1408; idx += 256) sW1[idx] = W1[idx];
        if (tid < 128) sb1[tid] = b1[tid];
        __syncthreads();
        int t8 = (b - 1250) * 256 + tid;    // [0, NEP*16)
        int ch = t8 & 63;
        int s4 = (t8 >> 6) & 3;
        int g16 = t8 >> 8;
        int m = ch & 15, q = ch >> 4;       // lane-linear content
        int e = g16 * 16 + m;
        int kb = 32 * s4 + q * 8;
        halfT v[8];
        if (e < NE){
            const float* xr = ea + (size_t)e * 11;
            float xv[11];
            #pragma unroll
            for (int f = 0; f < 11; f++) xv[f] = xr[f];
            #pragma unroll
            for (int i8 = 0; i8 < 8; i8++){
                int k = kb + i8;
                const float* wr = &sW1[k * 11];
                float s = sb1[k];
                #pragma unroll
                for (int f = 0; f < 11; f++) s += xv[f] * wr[f];
                v[i8] = (halfT)fmaxf(s, 0.f);
            }
        } else {
            #pragma unroll
            for (int i8 = 0; i8 < 8; i8++) v[i8] = (halfT)0.f;
        }
        *(half8*)(ehF + (size_t)t8 * 8) = *(half8*)v;
    } else if (b < 8022){
        int gid = (b - 7506) * 256 + tid;   // 129*2*64*8 = 132096
        int i8 = gid & 7;
        int ch = (gid >> 3) & 63;
        int nt = (gid >> 9) & 1;
        int ks = gid >> 10;
        int m = ch & 15, q = ch >> 4;       // lane-linear content
        int o = nt * 16 + m;
        float v;
        if (ks < 128){
            int c = ks >> 2;
            int k = 32 * (ks & 3) + q * 8 + i8;
            v = W2[(size_t)(c * 32 + o) * 128 + k];
        } else {
            int c = q * 8 + i8;
            v = b2[c * 32 + o];
        }
        BfF[gid] = (halfT)v;
    } else if (b < 8413){
        int e = (b - 8022) * 256 + tid;
        if (e < NE) atomicAdd(&deg[dstA[e]], 1.f);
    } else if (b < 8493){
        int t = (b - 8413) * 256 + tid;     // 20480
        if (t < 3072){ int k = t / 96, j = t % 96; WgT[t] = gWih[(size_t)j * 32 + k]; }
        else if (t < 6144){ int t2 = t - 3072; int k = t2 / 96, j = t2 % 96; WhT[t2] = gWhh[(size_t)j * 32 + k]; }
        else if (t < 14336){ int t2 = t - 6144; int k = t2 >> 7, j = t2 & 127; lWihT[t2] = lWih[(size_t)j * 64 + k]; }
        else if (t < 18432){ int t2 = t - 14336; int k = t2 >> 7, j = t2 & 127; lWhhT[t2] = lWhh[(size_t)j * 32 + k]; }
        else { int t2 = t - 18432; int k = t2 >> 5, c = t2 & 31; lin1T[t2] = lin1_W[(size_t)c * 64 + k]; }
    } else {
        int g = (b - 8493) * 256 + tid;
        if (g > NB) return;
        int lo = 0, hi = NN;
        while (lo < hi){
            int mid = (lo + hi) >> 1;
            if (batch[mid] < g) lo = mid + 1; else hi = mid;
        }
        starts[g] = lo;
    }
}

// =====================================================================
// k_msg4 R12: 512-thread blocks (8 waves share one LDS B staging) --
// halves L2 B-traffic and doubles waves/SIMD (4) for latency hiding.
// Per-wave compute identical to R11 (32 edges/wave, full K).
// =====================================================================
__global__ __launch_bounds__(512, 4) void k_msg4(
    const halfT* __restrict__ ehF, const halfT* __restrict__ BfF,
    const halfT* __restrict__ hH,
    const int* __restrict__ src, const int* __restrict__ dst,
    float* __restrict__ aggr)
{
    __shared__ halfT sB[2][8192];        // 2 x 16KB
    int tid = threadIdx.x;               // 0..511
    int l = tid & 63;
    int wid = blockIdx.x * 8 + (tid >> 6);
    int m = l & 15, q = l >> 4;
    int eb = wid * 32;
    // stage group 0 -> LDS (512 threads x 2 half8 = 16KB)
    half8 pre[2];
    #pragma unroll
    for (int p = 0; p < 2; p++)
        pre[p] = *(const half8*)(BfF + (size_t)(p * 512 + tid) * 8);
    #pragma unroll
    for (int p = 0; p < 2; p++)
        *(half8*)(&sB[0][(p * 512 + tid) * 8]) = pre[p];
    // per-wave operand fragments (latency overlaps staging)
    half8 u0[4], u1[4], ub0, ub1;
    {
        int e0 = eb + m;      int se0 = (e0 < NE) ? src[e0] : 0;
        int e1 = eb + 16 + m; int se1 = (e1 < NE) ? src[e1] : 0;
        const halfT* p0 = hH + (size_t)se0 * 32;
        const halfT* p1 = hH + (size_t)se1 * 32;
        #pragma unroll
        for (int j = 0; j < 4; j++){
            u0[j] = *(const half8*)(p0 + j * 8);
            u1[j] = *(const half8*)(p1 + j * 8);
        }
        ub0 = *(const half8*)(p0 + q * 8);
        ub1 = *(const half8*)(p1 + q * 8);
    }
    half8 eh0[4], eh1[4];
    {
        int g0 = eb >> 4;
        #pragma unroll
        for (int s = 0; s < 4; s++){
            eh0[s] = *(const half8*)(ehF + ((size_t)(g0 * 4 + s) * 64 + l) * 8);
            eh1[s] = *(const half8*)(ehF + ((size_t)((g0 + 1) * 4 + s) * 64 + l) * 8);
        }
    }
    __syncthreads();
    // prefetch group 1 into regs
    #pragma unroll
    for (int p = 0; p < 2; p++)
        pre[p] = *(const half8*)(BfF + (size_t)8192 + (size_t)(p * 512 + tid) * 8);
    f32x4 acc00 = {0,0,0,0}, acc01 = {0,0,0,0}, acc10 = {0,0,0,0}, acc11 = {0,0,0,0};
    #pragma unroll
    for (int g = 0; g < 16; g++){
        const int cur = g & 1;
        #pragma unroll
        for (int j = 0; j < 8; j++){
            const int ks = g * 8 + j;
            half8 b0 = *(const half8*)(&sB[cur][(j * 2 + 0) * 512 + l * 8]);
            half8 b1 = *(const half8*)(&sB[cur][(j * 2 + 1) * 512 + l * 8]);
            const int c = ks >> 2, s = ks & 3;
            halfT uc0 = u0[c >> 3][c & 7];
            halfT uc1 = u1[c >> 3][c & 7];
            half8 a0 = eh0[s] * uc0;
            half8 a1 = eh1[s] * uc1;
            acc00 = __builtin_amdgcn_mfma_f32_16x16x32_f16(a0, b0, acc00, 0, 0, 0);
            acc01 = __builtin_amdgcn_mfma_f32_16x16x32_f16(a0, b1, acc01, 0, 0, 0);
            acc10 = __builtin_amdgcn_mfma_f32_16x16x32_f16(a1, b0, acc10, 0, 0, 0);
            acc11 = __builtin_amdgcn_mfma_f32_16x16x32_f16(a1, b1, acc11, 0, 0, 0);
        }
        if (g + 1 < 16){
            #pragma unroll
            for (int p = 0; p < 2; p++)
                *(half8*)(&sB[cur ^ 1][(p * 512 + tid) * 8]) = pre[p];
            if (g + 2 < 16){
                #pragma unroll
                for (int p = 0; p < 2; p++)
                    pre[p] = *(const half8*)(BfF + (size_t)(g + 2) * 8192 + (size_t)(p * 512 + tid) * 8);
            }
        }
        __syncthreads();
    }
    {   // bias K-tile (ks = 128) straight from global (L2-hot, one shot)
        half8 b0 = *(const half8*)(BfF + (size_t)256 * 512 + l * 8);
        half8 b1 = *(const half8*)(BfF + (size_t)257 * 512 + l * 8);
        acc00 = __builtin_amdgcn_mfma_f32_16x16x32_f16(ub0, b0, acc00, 0, 0, 0);
        acc01 = __builtin_amdgcn_mfma_f32_16x16x32_f16(ub0, b1, acc01, 0, 0, 0);
        acc10 = __builtin_amdgcn_mfma_f32_16x16x32_f16(ub1, b0, acc10, 0, 0, 0);
        acc11 = __builtin_amdgcn_mfma_f32_16x16x32_f16(ub1, b1, acc11, 0, 0, 0);
    }
    // scatter: lane holds msg[e = eb+G*16+q*4+r][o = nt*16+m]
    #pragma unroll
    for (int r = 0; r < 4; r++){
        int ea0 = eb + q * 4 + r;
        if (ea0 < NE){
            int d = dst[ea0];
            atomicAdd(&aggr[(size_t)d * 32 + m],      acc00[r]);
            atomicAdd(&aggr[(size_t)d * 32 + 16 + m], acc01[r]);
        }
        int ea1 = eb + 16 + q * 4 + r;
        if (ea1 < NE){
            int d = dst[ea1];
            atomicAdd(&aggr[(size_t)d * 32 + m],      acc10[r]);
            atomicAdd(&aggr[(size_t)d * 32 + 16 + m], acc11[r]);
        }
    }
}

// =====================================================================
// k_gru: wave-parallel (lane = output channel, 32 lanes per node).  [unchanged]
// =====================================================================
__global__ __launch_bounds__(256) void k_gru(
    float* __restrict__ aggr, const float* __restrict__ deg, float* __restrict__ h,
    halfT* __restrict__ hH,
    const float* __restrict__ rootW, const float* __restrict__ cb,
    const float* __restrict__ WgT, const float* __restrict__ WhT,
    const float* __restrict__ gbih, const float* __restrict__ gbhh)
{
    int tid = threadIdx.x;
    int i = blockIdx.x * 8 + (tid >> 5);
    int c = tid & 31;
    size_t base = (size_t)i * 32 + c;
    float hq = h[base];
    float av = aggr[base];
    aggr[base] = 0.f;
    float invd = 1.f / fmaxf(deg[i], 1.f);
    float mv = av * invd + cb[c];
    #pragma unroll 8
    for (int k = 0; k < 32; k++)
        mv += __shfl(hq, k, 32) * rootW[k * 32 + c];
    mv = fmaxf(mv, 0.f);
    float gr = gbih[c],      hr = gbhh[c];
    float gz = gbih[32 + c], hz = gbhh[32 + c];
    float gn = gbih[64 + c], hn = gbhh[64 + c];
    #pragma unroll 4
    for (int k = 0; k < 32; k++){
        float mk = __shfl(mv, k, 32);
        float hk = __shfl(hq, k, 32);
        const float* wg = WgT + k * 96;
        const float* wh = WhT + k * 96;
        gr += mk * wg[c];      hr += hk * wh[c];
        gz += mk * wg[32 + c]; hz += hk * wh[32 + c];
        gn += mk * wg[64 + c]; hn += hk * wh[64 + c];
    }
    float r = sigf(gr + hr);
    float z = sigf(gz + hz);
    float n = tanhf(gn + r * hn);
    float hnew = (1.f - z) * n + z * hq;
    h[base] = hnew;
    hH[base] = (halfT)hnew;
}

// =====================================================================
// k_s2s: LDS-cached Set2Set + final MLP.  [unchanged from R11]
// =====================================================================
__global__ __launch_bounds__(64) void k_s2s(
    const float* __restrict__ h, const int* __restrict__ starts,
    const float* __restrict__ lWihT, const float* __restrict__ lWhhT,
    const float* __restrict__ lbih, const float* __restrict__ lbhh,
    const float* __restrict__ lin1T, const float* __restrict__ lin1_b,
    const float* __restrict__ lin2W, const float* __restrict__ lin2b,
    float* __restrict__ e_buf, float* __restrict__ out)
{
    __shared__ float hl[MAXN * 33];
    __shared__ float al[MAXN];
    __shared__ float hsl[32];
    int g = blockIdx.x, l = threadIdx.x;
    int s0 = starts[g], s1 = starts[g + 1];
    int n = s1 - s0;
    int c = l & 31, grp = l >> 5;
    int nl = (n < MAXN) ? n : MAXN;
    for (int idx = l; idx < nl * 32; idx += 64)
        hl[(idx >> 5) * 33 + (idx & 31)] = h[(size_t)s0 * 32 + idx];
    __syncthreads();
    float qs = 0.f, hsv = 0.f, csv = 0.f;
    for (int t = 0; t < 3; t++){
        float a1 = lbih[l] + lbhh[l];
        float a2 = lbih[l + 64] + lbhh[l + 64];
        #pragma unroll 8
        for (int k = 0; k < 64; k++){
            float qk = __shfl(qs, k);
            a1 += qk * lWihT[k * 128 + l];
            a2 += qk * lWihT[k * 128 + 64 + l];
        }
        #pragma unroll 8
        for (int k = 0; k < 32; k++){
            float hk = __shfl(qs, k);
            a1 += hk * lWhhT[k * 128 + l];
            a2 += hk * lWhhT[k * 128 + 64 + l];
        }
        float gate1 = sigf(a1);
        float gate2 = (l < 32) ? tanhf(a2) : sigf(a2);
        float fv = __shfl(gate1, c + 32);
        float ov = __shfl(gate2, c + 32);
        if (l < 32){
            csv = fv * csv + gate1 * gate2;
            hsv = ov * tanhf(csv);
            hsl[l] = hsv;
        }
        __syncthreads();
        float lmax = -3.4e38f;
        for (int i = l; i < n; i += 64){
            const float* hr = (i < MAXN) ? &hl[i * 33] : &h[(size_t)(s0 + i) * 32];
            float p = 0.f;
            #pragma unroll
            for (int c2 = 0; c2 < 32; c2++) p += hr[c2] * hsl[c2];
            if (i < MAXN) al[i] = p; else e_buf[s0 + i] = p;
            lmax = fmaxf(lmax, p);
        }
        #pragma unroll
        for (int o = 1; o < 64; o <<= 1) lmax = fmaxf(lmax, __shfl_xor(lmax, o));
        float lsum = 0.f;
        for (int i = l; i < n; i += 64){
            float e = (i < MAXN) ? al[i] : e_buf[s0 + i];
            float a = expf(e - lmax);
            if (i < MAXN) al[i] = a; else e_buf[s0 + i] = a;
            lsum += a;
        }
        #pragma unroll
        for (int o = 1; o < 64; o <<= 1) lsum += __shfl_xor(lsum, o);
        float inv = (lsum > 0.f) ? 1.f / lsum : 0.f;
        __syncthreads();
        float acc = 0.f;
        for (int i = grp; i < n; i += 2){
            float a = (i < MAXN) ? al[i] : e_buf[s0 + i];
            const float* hr = (i < MAXN) ? &hl[i * 33] : &h[(size_t)(s0 + i) * 32];
            acc += a * hr[c];
        }
        acc *= inv;
        acc += __shfl_xor(acc, 32);
        qs = (l < 32) ? hsv : acc;
        __syncthreads();
    }
    float s = lin1_b[c];
    #pragma unroll 8
    for (int k = 0; k < 64; k++){
        float qk = __shfl(qs, k);
        s += qk * lin1T[k * 32 + c];
    }
    float pp = (l < 32) ? fmaxf(s, 0.f) * lin2W[c] : 0.f;
    pp += __shfl_xor(pp, 1);  pp += __shfl_xor(pp, 2);
    pp += __shfl_xor(pp, 4);  pp += __shfl_xor(pp, 8);
    pp += __shfl_xor(pp, 16); pp += __shfl_xor(pp, 32);
    if (l == 0) out[g] = pp + lin2b[0];
}

extern "C" void kernel_launch(void* const* d_in, const int* in_sizes, int n_in,
                              void* d_out, int out_size, void* d_ws, size_t ws_size,
                              hipStream_t stream){
    (void)in_sizes; (void)n_in; (void)out_size;
    const float* x        = (const float*)d_in[0];
    const float* ea       = (const float*)d_in[1];
    const int*   ei       = (const int*)d_in[2];
    const int*   batch    = (const int*)d_in[3];
    const float* lin0_W   = (const float*)d_in[4];
    const float* lin0_b   = (const float*)d_in[5];
    const float* mlp_W1   = (const float*)d_in[6];
    const float* mlp_b1   = (const float*)d_in[7];
    const float* mlp_W2   = (const float*)d_in[8];
    const float* mlp_b2   = (const float*)d_in[9];
    const float* root_W   = (const float*)d_in[10];
    const float* conv_b   = (const float*)d_in[11];
    const float* gWih     = (const float*)d_in[12];
    const float* gWhh     = (const float*)d_in[13];
    const float* gbih     = (const float*)d_in[14];
    const float* gbhh     = (const float*)d_in[15];
    const float* lWih     = (const float*)d_in[16];
    const float* lWhh     = (const float*)d_in[17];
    const float* lbih     = (const float*)d_in[18];
    const float* lbhh     = (const float*)d_in[19];
    const float* lin1_W   = (const float*)d_in[20];
    const float* lin1_b   = (const float*)d_in[21];
    const float* lin2_W   = (const float*)d_in[22];
    const float* lin2_b   = (const float*)d_in[23];
    const int* src = ei;
    const int* dst = ei + NE;
    float* out = (float*)d_out;

    char* w = (char*)d_ws;
    size_t off = 0;
    auto alloc = [&](size_t bytes) -> void* {
        void* p = w + off;
        off = (off + bytes + 255) & ~(size_t)255;
        return p;
    };
    float* deg    = (float*)alloc((size_t)NN * 4);            // contiguous with aggr
    float* aggr   = (float*)alloc((size_t)NN * 32 * 4);
    float* h      = (float*)alloc((size_t)NN * 32 * 4);
    halfT* hH     = (halfT*)alloc((size_t)NN * 32 * 2);
    halfT* ehF    = (halfT*)alloc((size_t)NEP * 128 * 2);
    halfT* BfF    = (halfT*)alloc((size_t)129 * 2 * 64 * 8 * 2);
    int*   starts = (int*)alloc((size_t)(NB + 1) * 4);
    float* WgT    = (float*)alloc((size_t)3072 * 4);
    float* WhT    = (float*)alloc((size_t)3072 * 4);
    float* lWihT  = (float*)alloc((size_t)8192 * 4);
    float* lWhhT  = (float*)alloc((size_t)4096 * 4);
    float* lin1T  = (float*)alloc((size_t)2048 * 4);
    float* e_buf  = (float*)alloc((size_t)NN * 4);
    if (ws_size < off) return;   // cannot run

    hipMemsetAsync(deg, 0, (size_t)NN * 4 + (size_t)NN * 32 * 4, stream);

    k_setup<<<8498, 256, 0, stream>>>(x, lin0_W, lin0_b, ea, mlp_W1, mlp_b1,
        mlp_W2, mlp_b2, dst, batch, gWih, gWhh, lWih, lWhh, lin1_W,
        h, hH, ehF, BfF, deg, WgT, WhT, lWihT, lWhhT, lin1T, starts);

    for (int t = 0; t < 3; t++){
        k_msg4<<<NEP / 256, 512, 0, stream>>>(ehF, BfF, hH, src, dst, aggr);
        k_gru<<<NN / 8, 256, 0, stream>>>(aggr, deg, h, hH, root_W, conv_b,
                                          WgT, WhT, gbih, gbhh);
    }
    k_s2s<<<NB, 64, 0, stream>>>(h, starts, lWihT, lWhhT, lbih, lbhh,
                                 lin1T, lin1_b, lin2_W, lin2_b, e_buf, out);
}